// Round 1
// baseline (104286.389 us; speedup 1.0000x reference)
//
#include <hip/hip_runtime.h>
#include <hip/hip_cooperative_groups.h>

typedef __attribute__((ext_vector_type(8))) short short8;
typedef __attribute__((ext_vector_type(4))) short short4v;
typedef __attribute__((ext_vector_type(4))) float f32x4;

namespace cg = cooperative_groups;

__device__ __forceinline__ short f2bf(float x) {
  union { float f; unsigned u; } v; v.f = x;
  unsigned r = v.u + 0x7fffu + ((v.u >> 16) & 1u);   // RNE
  return (short)(r >> 16);
}
__device__ __forceinline__ float bf2f(short b) {
  union { unsigned u; float f; } v; v.u = ((unsigned)(unsigned short)b) << 16;
  return v.f;
}

#define GLOAD_LDS16(g, l) __builtin_amdgcn_global_load_lds( \
    (const __attribute__((address_space(1))) void*)(g),     \
    (__attribute__((address_space(3))) void*)(l), 16, 0, 0)

// ---------------- f32 -> bf16 conversion ----------------
__global__ void k_cvt(const float* __restrict__ s, short* __restrict__ d, int n) {
  int stride = gridDim.x * blockDim.x * 4;
  for (int i = (blockIdx.x * blockDim.x + threadIdx.x) * 4; i < n; i += stride) {
    float4 v = *(const float4*)(s + i);
    short4v o;
    o.x = f2bf(v.x); o.y = f2bf(v.y); o.z = f2bf(v.z); o.w = f2bf(v.w);
    *(short4v*)(d + i) = o;
  }
}

// ---------------- combined bias (fwd 0:4096, rev 4096:8192) ----------------
__global__ void k_bias(const float* __restrict__ bif, const float* __restrict__ bhf,
                       const float* __restrict__ bir, const float* __restrict__ bhr,
                       float* __restrict__ o) {
  int i = blockIdx.x * 256 + threadIdx.x;
  o[i] = (i < 4096) ? (bif[i] + bhf[i]) : (bir[i - 4096] + bhr[i - 4096]);
}

// ---------------- input GEMM: C[M][N] = A[M][K] * Bt[N][K]^T + bias, bf16 out ----
// m97-structure: 128x128 tile, BK=64, 4 waves, global_load_lds width 16.
__global__ void __launch_bounds__(256) k_gemm(
    const short* __restrict__ A, const short* __restrict__ Bt,
    const float* __restrict__ bias, short* __restrict__ C,
    int M, int N, int K)
{
  __shared__ short Al[128 * 64];
  __shared__ short Bl[128 * 64];
  const int nm = M >> 7;
  int wg = blockIdx.x;
  int q = gridDim.x >> 3;                   // gridDim.x % 8 == 0 (8192)
  wg = (wg & 7) * q + (wg >> 3);            // XCD-aware swizzle (bijective)
  const int mt = wg % nm, nt = wg / nm;
  const int tid = threadIdx.x, lane = tid & 63, w = tid >> 6;
  const int wr = w >> 1, wc = w & 1;
  const short* Ab = A + (size_t)(mt * 128) * K;
  const short* Bb = Bt + (size_t)(nt * 128) * K;
  f32x4 acc[4][4] = {};
  const int lrow = lane >> 3, lseg = lane & 7;

  for (int kt = 0; kt < K; kt += 64) {
#pragma unroll
    for (int s = 0; s < 4; ++s) {
      int chunk = s * 4 + w;                // wave-uniform LDS base
      int r = chunk * 8 + lrow;
      GLOAD_LDS16(Ab + (size_t)r * K + kt + lseg * 8, &Al[chunk * 512]);
      GLOAD_LDS16(Bb + (size_t)r * K + kt + lseg * 8, &Bl[chunk * 512]);
    }
    __syncthreads();
#pragma unroll
    for (int kk = 0; kk < 2; ++kk) {
      short8 af[4], bfr[4];
#pragma unroll
      for (int i = 0; i < 4; ++i) {
        af[i]  = *(const short8*)&Al[(wr * 64 + i * 16 + (lane & 15)) * 64 + kk * 32 + (lane >> 4) * 8];
        bfr[i] = *(const short8*)&Bl[(wc * 64 + i * 16 + (lane & 15)) * 64 + kk * 32 + (lane >> 4) * 8];
      }
#pragma unroll
      for (int i = 0; i < 4; ++i)
#pragma unroll
        for (int j = 0; j < 4; ++j)
          acc[i][j] = __builtin_amdgcn_mfma_f32_16x16x32_bf16(af[i], bfr[j], acc[i][j], 0, 0, 0);
    }
    __syncthreads();
  }

  const int r0 = mt * 128 + wr * 64, c0n = nt * 128 + wc * 64;
#pragma unroll
  for (int i = 0; i < 4; ++i) {
#pragma unroll
    for (int j = 0; j < 4; ++j) {
      int col = c0n + j * 16 + (lane & 15);
      float bv = bias[col];
#pragma unroll
      for (int r = 0; r < 4; ++r) {
        int row = r0 + i * 16 + (lane >> 4) * 4 + r;
        C[(size_t)row * N + col] = f2bf(acc[i][j][r] + bv);
      }
    }
  }
}

// ---------------- persistent bidirectional scan (cooperative) ----------------
// 256 WGs x 256 threads. WG = (dir = blk>>7, wid = blk&127) owns h-cols [wid*8, wid*8+8).
// W_hh fragments held in registers (short8 wf[32]); h double-buffered bf16 in global.
template <bool LAST>
__global__ void __launch_bounds__(256, 1) k_scan(
    const short* __restrict__ gx,     // [16384][8192] bf16 (bias included)
    const short* __restrict__ whh,    // [8192][1024] bf16 (fwd rows 0:4096, rev 4096:8192)
    const float* __restrict__ h0,     // [6][32][1024]
    const float* __restrict__ c0,
    short* __restrict__ hbuf,         // [2 parity][2 dir][32][1024] bf16
    void* __restrict__ yout,          // bf16 [512][32][2048] or f32 (LAST)
    int layer)
{
  const int tid = threadIdx.x, lane = tid & 63, w = tid >> 6;
  const int dir = blockIdx.x >> 7, wid = blockIdx.x & 127;
  const int hc0 = wid * 8;
  const int m = w & 1, n = w >> 1;          // wave quadrant of the 32x32 gate tile
  __shared__ float gateL[32][33];

  // --- weights into registers: lane holds B-frag (col = local gate row, 8 k per ks) ---
  short8 wf[32];
  {
    const int lcol = n * 16 + (lane & 15);                       // 0..31: [i f g o] x 8 cols
    const int grow = dir * 4096 + (lcol >> 3) * 1024 + hc0 + (lcol & 7);
    const short* wp = whh + (size_t)grow * 1024 + (lane >> 4) * 8;
#pragma unroll
    for (int ks = 0; ks < 32; ++ks) wf[ks] = *(const short8*)(wp + ks * 32);
  }

  // --- state init ---
  const int ub = tid >> 3, uc = tid & 7;    // update mapping: (batch, col-within-8)
  const int sidx = (2 * layer + dir) * 32 * 1024 + ub * 1024 + hc0 + uc;
  float c_reg = c0[sidx];
  hbuf[(dir * 32 + ub) * 1024 + hc0 + uc] = f2bf(h0[sidx]);      // parity-0 buffer
  const int ab = m * 16 + (lane & 15);      // batch row for A-fragments

  cg::grid_group grid = cg::this_grid();
  __threadfence();
  grid.sync();

  int p = 0;
  for (int ts = 0; ts < 512; ++ts) {
    const int t = dir ? (511 - ts) : ts;

    // --- gates = h @ Whh^T via MFMA; A-frags straight from global (L1/L2-hot) ---
    const short* ap = hbuf + ((size_t)(p * 2 + dir) * 32 + ab) * 1024 + (lane >> 4) * 8;
    short8 af[32];
#pragma unroll
    for (int ks = 0; ks < 32; ++ks) af[ks] = *(const short8*)(ap + ks * 32);
    f32x4 acc0 = {}, acc1 = {};
#pragma unroll
    for (int ks = 0; ks < 32; ks += 2) {
      acc0 = __builtin_amdgcn_mfma_f32_16x16x32_bf16(af[ks],     wf[ks],     acc0, 0, 0, 0);
      acc1 = __builtin_amdgcn_mfma_f32_16x16x32_bf16(af[ks + 1], wf[ks + 1], acc1, 0, 0, 0);
    }
    f32x4 acc = acc0 + acc1;
#pragma unroll
    for (int r = 0; r < 4; ++r)
      gateL[n * 16 + (lane & 15)][m * 16 + (lane >> 4) * 4 + r] = acc[r];
    __syncthreads();

    // --- elementwise update: thread owns (b=ub, col=hc0+uc) ---
    const short* gp = gx + (size_t)(t * 32 + ub) * 8192 + dir * 4096 + hc0 + uc;
    float gi = gateL[uc     ][ub] + bf2f(gp[0]);
    float gf = gateL[8 + uc ][ub] + bf2f(gp[1024]);
    float gg = gateL[16 + uc][ub] + bf2f(gp[2048]);
    float go = gateL[24 + uc][ub] + bf2f(gp[3072]);
    float i_ = fminf(fmaxf(0.2f * gi + 0.5f, 0.f), 1.f);
    float f_ = fminf(fmaxf(0.2f * gf + 0.5f, 0.f), 1.f);
    float g_ = fminf(fmaxf(gg, -1.f), 1.f);
    float o_ = fminf(fmaxf(0.2f * go + 0.5f, 0.f), 1.f);
    c_reg = f_ * c_reg + i_ * g_;
    const float h = o_ * fminf(fmaxf(c_reg, -1.f), 1.f);
    const short hb = f2bf(h);

    hbuf[((size_t)((p ^ 1) * 2 + dir) * 32 + ub) * 1024 + hc0 + uc] = hb;
    const size_t yi = (size_t)(t * 32 + ub) * 2048 + dir * 1024 + hc0 + uc;
    if (LAST) ((float*)yout)[yi] = h;
    else      ((short*)yout)[yi] = hb;

    __threadfence();
    grid.sync();
    p ^= 1;
  }
}

// ---------------- host ----------------
extern "C" void kernel_launch(void* const* d_in, const int* in_sizes, int n_in,
                              void* d_out, int out_size, void* d_ws, size_t ws_size,
                              hipStream_t stream)
{
  const float* x  = (const float*)d_in[0];
  const float* h0 = (const float*)d_in[1];
  const float* c0 = (const float*)d_in[2];
  auto W = [&](int l, int d, int k) { return (const float*)d_in[3 + l * 8 + d * 4 + k]; };
  // k: 0=w_ih, 1=w_hh, 2=b_ih, 3=b_hh

  char* base = (char*)d_ws;
  size_t off = 0;
  auto alloc = [&](size_t bytes) {
    void* p = base + off;
    off = (off + bytes + 255) & ~(size_t)255;
    return p;
  };
  short* xb    = (short*)alloc(16384ull * 320 * 2);
  short* wih0  = (short*)alloc(8192ull * 320 * 2);
  short* wih1  = (short*)alloc(8192ull * 2048 * 2);
  short* wih2  = (short*)alloc(8192ull * 2048 * 2);
  short* whh0  = (short*)alloc(8192ull * 1024 * 2);
  short* whh1  = (short*)alloc(8192ull * 1024 * 2);
  short* whh2  = (short*)alloc(8192ull * 1024 * 2);
  float* bias0 = (float*)alloc(8192ull * 4);
  float* bias1 = (float*)alloc(8192ull * 4);
  float* bias2 = (float*)alloc(8192ull * 4);
  short* gx    = (short*)alloc(16384ull * 8192 * 2);
  short* y1    = (short*)alloc(16384ull * 2048 * 2);
  short* y2    = (short*)alloc(16384ull * 2048 * 2);
  short* hbuf  = (short*)alloc(2ull * 2 * 32 * 1024 * 2);
  (void)ws_size; (void)in_sizes; (void)n_in; (void)out_size;

  auto cvt = [&](const float* s, short* d, size_t n) {
    size_t want = (n / 4 + 255) / 256;
    int blocks = (int)(want > 2048 ? 2048 : want);
    k_cvt<<<dim3(blocks), dim3(256), 0, stream>>>(s, d, (int)n);
  };

  cvt(x, xb, 16384ull * 320);
  short* wihs[3] = { wih0, wih1, wih2 };
  short* whhs[3] = { whh0, whh1, whh2 };
  float* biases[3] = { bias0, bias1, bias2 };
  for (int l = 0; l < 3; ++l) {
    size_t kin = (l == 0) ? 320 : 2048;
    cvt(W(l, 0, 0), wihs[l],                  4096 * kin);
    cvt(W(l, 1, 0), wihs[l] + 4096 * kin,     4096 * kin);
    cvt(W(l, 0, 1), whhs[l],                  4096ull * 1024);
    cvt(W(l, 1, 1), whhs[l] + 4096ull * 1024, 4096ull * 1024);
    k_bias<<<dim3(32), dim3(256), 0, stream>>>(W(l, 0, 2), W(l, 0, 3), W(l, 1, 2), W(l, 1, 3), biases[l]);
  }

  const int M = 16384, N = 8192;

  // ---- layer 0 ----
  k_gemm<<<dim3((M / 128) * (N / 128)), dim3(256), 0, stream>>>(xb, wih0, bias0, gx, M, N, 320);
  {
    const short* gxc = gx; const short* whhc = whh0; short* hb = hbuf;
    void* yo = (void*)y1; int layer = 0;
    void* args[] = { &gxc, &whhc, &h0, &c0, &hb, &yo, &layer };
    hipLaunchCooperativeKernel(k_scan<false>, dim3(256), dim3(256), args, 0, stream);
  }
  // ---- layer 1 ----
  k_gemm<<<dim3((M / 128) * (N / 128)), dim3(256), 0, stream>>>(y1, wih1, bias1, gx, M, N, 2048);
  {
    const short* gxc = gx; const short* whhc = whh1; short* hb = hbuf;
    void* yo = (void*)y2; int layer = 1;
    void* args[] = { &gxc, &whhc, &h0, &c0, &hb, &yo, &layer };
    hipLaunchCooperativeKernel(k_scan<false>, dim3(256), dim3(256), args, 0, stream);
  }
  // ---- layer 2 ----
  k_gemm<<<dim3((M / 128) * (N / 128)), dim3(256), 0, stream>>>(y2, wih2, bias2, gx, M, N, 2048);
  {
    const short* gxc = gx; const short* whhc = whh2; short* hb = hbuf;
    void* yo = d_out; int layer = 2;
    void* args[] = { &gxc, &whhc, &h0, &c0, &hb, &yo, &layer };
    hipLaunchCooperativeKernel(k_scan<true>, dim3(256), dim3(256), args, 0, stream);
  }
}

// Round 2
// 24419.832 us; speedup vs baseline: 4.2706x; 4.2706x over previous
//
#include <hip/hip_runtime.h>

typedef __attribute__((ext_vector_type(8))) short short8;
typedef __attribute__((ext_vector_type(4))) short short4v;
typedef __attribute__((ext_vector_type(4))) float f32x4;

__device__ __forceinline__ short f2bf(float x) {
  union { float f; unsigned u; } v; v.f = x;
  unsigned r = v.u + 0x7fffu + ((v.u >> 16) & 1u);   // RNE
  return (short)(r >> 16);
}
__device__ __forceinline__ float bf2f(short b) {
  union { unsigned u; float f; } v; v.u = ((unsigned)(unsigned short)b) << 16;
  return v.f;
}

#define GLOAD_LDS16(g, l) __builtin_amdgcn_global_load_lds( \
    (const __attribute__((address_space(1))) void*)(g),     \
    (__attribute__((address_space(3))) void*)(l), 16, 0, 0)

// ---------------- f32 -> bf16 conversion ----------------
__global__ void k_cvt(const float* __restrict__ s, short* __restrict__ d, int n) {
  int stride = gridDim.x * blockDim.x * 4;
  for (int i = (blockIdx.x * blockDim.x + threadIdx.x) * 4; i < n; i += stride) {
    float4 v = *(const float4*)(s + i);
    short4v o;
    o.x = f2bf(v.x); o.y = f2bf(v.y); o.z = f2bf(v.z); o.w = f2bf(v.w);
    *(short4v*)(d + i) = o;
  }
}

// ---------------- combined bias (fwd 0:4096, rev 4096:8192) ----------------
__global__ void k_bias(const float* __restrict__ bif, const float* __restrict__ bhf,
                       const float* __restrict__ bir, const float* __restrict__ bhr,
                       float* __restrict__ o) {
  int i = blockIdx.x * 256 + threadIdx.x;
  o[i] = (i < 4096) ? (bif[i] + bhf[i]) : (bir[i - 4096] + bhr[i - 4096]);
}

// ---------------- zero the barrier counters (before each scan) ----------------
__global__ void k_zero(int* __restrict__ p) { p[threadIdx.x * 64] = 0; }

// ---------------- input GEMM: C[M][N] = A[M][K] * Bt[N][K]^T + bias, bf16 out ----
__global__ void __launch_bounds__(256) k_gemm(
    const short* __restrict__ A, const short* __restrict__ Bt,
    const float* __restrict__ bias, short* __restrict__ C,
    int M, int N, int K)
{
  __shared__ short Al[128 * 64];
  __shared__ short Bl[128 * 64];
  const int nm = M >> 7;
  int wg = blockIdx.x;
  int q = gridDim.x >> 3;                   // gridDim.x % 8 == 0 (8192)
  wg = (wg & 7) * q + (wg >> 3);            // XCD-aware swizzle (bijective)
  const int mt = wg % nm, nt = wg / nm;
  const int tid = threadIdx.x, lane = tid & 63, w = tid >> 6;
  const int wr = w >> 1, wc = w & 1;
  const short* Ab = A + (size_t)(mt * 128) * K;
  const short* Bb = Bt + (size_t)(nt * 128) * K;
  f32x4 acc[4][4] = {};
  const int lrow = lane >> 3, lseg = lane & 7;

  for (int kt = 0; kt < K; kt += 64) {
#pragma unroll
    for (int s = 0; s < 4; ++s) {
      int chunk = s * 4 + w;                // wave-uniform LDS base
      int r = chunk * 8 + lrow;
      GLOAD_LDS16(Ab + (size_t)r * K + kt + lseg * 8, &Al[chunk * 512]);
      GLOAD_LDS16(Bb + (size_t)r * K + kt + lseg * 8, &Bl[chunk * 512]);
    }
    __syncthreads();
#pragma unroll
    for (int kk = 0; kk < 2; ++kk) {
      short8 af[4], bfr[4];
#pragma unroll
      for (int i = 0; i < 4; ++i) {
        af[i]  = *(const short8*)&Al[(wr * 64 + i * 16 + (lane & 15)) * 64 + kk * 32 + (lane >> 4) * 8];
        bfr[i] = *(const short8*)&Bl[(wc * 64 + i * 16 + (lane & 15)) * 64 + kk * 32 + (lane >> 4) * 8];
      }
#pragma unroll
      for (int i = 0; i < 4; ++i)
#pragma unroll
        for (int j = 0; j < 4; ++j)
          acc[i][j] = __builtin_amdgcn_mfma_f32_16x16x32_bf16(af[i], bfr[j], acc[i][j], 0, 0, 0);
    }
    __syncthreads();
  }

  const int r0 = mt * 128 + wr * 64, c0n = nt * 128 + wc * 64;
#pragma unroll
  for (int i = 0; i < 4; ++i) {
#pragma unroll
    for (int j = 0; j < 4; ++j) {
      int col = c0n + j * 16 + (lane & 15);
      float bv = bias[col];
#pragma unroll
      for (int r = 0; r < 4; ++r) {
        int row = r0 + i * 16 + (lane >> 4) * 4 + r;
        C[(size_t)row * N + col] = f2bf(acc[i][j][r] + bv);
      }
    }
  }
}

// ---------------- cross-WG barrier without L2 writeback ----------------
// Requires: all cross-WG-visible data stored with agent-scope atomics
// (sc0|sc1 write-through) BEFORE this call. vmcnt(0) puts them at the
// coherence point; counter RMW/loads are agent-coherent; acquire fence
// (buffer_inv, no writeback) drops stale clean lines before re-reading h.
__device__ __forceinline__ void xbar(int* ctr, int target, int tid) {
  asm volatile("s_waitcnt vmcnt(0)" ::: "memory");
  __syncthreads();
  if (tid == 0) {
    __hip_atomic_fetch_add(ctr, 1, __ATOMIC_RELAXED, __HIP_MEMORY_SCOPE_AGENT);
    while (__hip_atomic_load(ctr, __ATOMIC_RELAXED, __HIP_MEMORY_SCOPE_AGENT) < target)
      __builtin_amdgcn_s_sleep(2);
  }
  __syncthreads();
  __builtin_amdgcn_fence(__ATOMIC_ACQUIRE, "agent");
}

// ---------------- persistent bidirectional scan ----------------
// 256 WGs x 256 threads. WG = (dir = blk>>7, wid = blk&127) owns h-cols [wid*8, wid*8+8).
// W_hh fragments in registers; h double-buffered bf16 in global, published via
// agent-scope atomic stores; per-direction flag barrier (no grid.sync, no wbl2).
template <bool LAST>
__global__ void __launch_bounds__(256, 1) k_scan(
    const short* __restrict__ gx,     // [16384][8192] bf16 (bias included)
    const short* __restrict__ whh,    // [8192][1024] bf16 (fwd rows 0:4096, rev 4096:8192)
    const float* __restrict__ h0,     // [6][32][1024]
    const float* __restrict__ c0,
    short* __restrict__ hbuf,         // [2 parity][2 dir][32][1024] bf16
    void* __restrict__ yout,          // bf16 [512][32][2048] or f32 (LAST)
    int layer, int* __restrict__ bar) // bar[0]: dir0, bar[64]: dir1
{
  const int tid = threadIdx.x, lane = tid & 63, w = tid >> 6;
  const int dir = blockIdx.x >> 7, wid = blockIdx.x & 127;
  const int hc0 = wid * 8;
  const int m = w & 1, n = w >> 1;          // wave quadrant of the 32x32 gate tile
  __shared__ float gateL[32][33];
  int* ctr = bar + dir * 64;

  // --- weights into registers: lane holds B-frag (col = local gate row, 8 k per ks) ---
  short8 wf[32];
  {
    const int lcol = n * 16 + (lane & 15);                       // 0..31: [i f g o] x 8 cols
    const int grow = dir * 4096 + (lcol >> 3) * 1024 + hc0 + (lcol & 7);
    const short* wp = whh + (size_t)grow * 1024 + (lane >> 4) * 8;
#pragma unroll
    for (int ks = 0; ks < 32; ++ks) wf[ks] = *(const short8*)(wp + ks * 32);
  }

  // --- state init: 64 active threads, each owns (batch b, 4 h-cols) ---
  const int b4 = tid >> 1, cg = tid & 1, col0 = hc0 + cg * 4;
  float ca[4] = {0.f, 0.f, 0.f, 0.f};
  if (tid < 64) {
    const int sidx = ((2 * layer + dir) * 32 + b4) * 1024 + col0;
    float4 cv = *(const float4*)(c0 + sidx);
    ca[0] = cv.x; ca[1] = cv.y; ca[2] = cv.z; ca[3] = cv.w;
    float4 hv = *(const float4*)(h0 + sidx);
    union { unsigned long long u; short s[4]; } pk;
    pk.s[0] = f2bf(hv.x); pk.s[1] = f2bf(hv.y); pk.s[2] = f2bf(hv.z); pk.s[3] = f2bf(hv.w);
    size_t qi = (((size_t)dir * 32 + b4) * 1024 + col0) >> 2;    // parity 0
    __hip_atomic_store((unsigned long long*)hbuf + qi, pk.u,
                       __ATOMIC_RELAXED, __HIP_MEMORY_SCOPE_AGENT);
  }
  const int ab = m * 16 + (lane & 15);      // batch row for A-fragments

  xbar(ctr, 128, tid);

  int p = 0;
  for (int ts = 0; ts < 512; ++ts) {
    const int t = dir ? (511 - ts) : ts;

    // --- gates = h @ Whh^T via MFMA; A-frags from global (L2/L3, post-inv) ---
    const short* ap = hbuf + ((size_t)(p * 2 + dir) * 32 + ab) * 1024 + (lane >> 4) * 8;
    short8 af[32];
#pragma unroll
    for (int ks = 0; ks < 32; ++ks) af[ks] = *(const short8*)(ap + ks * 32);
    f32x4 acc0 = {}, acc1 = {}, acc2 = {}, acc3 = {};
#pragma unroll
    for (int ks = 0; ks < 32; ks += 4) {
      acc0 = __builtin_amdgcn_mfma_f32_16x16x32_bf16(af[ks],     wf[ks],     acc0, 0, 0, 0);
      acc1 = __builtin_amdgcn_mfma_f32_16x16x32_bf16(af[ks + 1], wf[ks + 1], acc1, 0, 0, 0);
      acc2 = __builtin_amdgcn_mfma_f32_16x16x32_bf16(af[ks + 2], wf[ks + 2], acc2, 0, 0, 0);
      acc3 = __builtin_amdgcn_mfma_f32_16x16x32_bf16(af[ks + 3], wf[ks + 3], acc3, 0, 0, 0);
    }
    f32x4 acc = (acc0 + acc1) + (acc2 + acc3);
#pragma unroll
    for (int r = 0; r < 4; ++r)
      gateL[n * 16 + (lane & 15)][m * 16 + (lane >> 4) * 4 + r] = acc[r];
    __syncthreads();

    // --- elementwise update: thread (tid<64) owns (b=b4, cols col0..col0+3) ---
    if (tid < 64) {
      const int c7 = cg * 4;
      const short* gp = gx + ((size_t)(t * 32 + b4)) * 8192 + dir * 4096 + col0;
      short4v gxi = *(const short4v*)(gp);
      short4v gxf = *(const short4v*)(gp + 1024);
      short4v gxg = *(const short4v*)(gp + 2048);
      short4v gxo = *(const short4v*)(gp + 3072);
      float hv[4];
      union { unsigned long long u; short s[4]; } pk;
#pragma unroll
      for (int j = 0; j < 4; ++j) {
        float gi = gateL[c7 + j][b4]      + bf2f(gxi[j]);
        float gf = gateL[8 + c7 + j][b4]  + bf2f(gxf[j]);
        float gg = gateL[16 + c7 + j][b4] + bf2f(gxg[j]);
        float go = gateL[24 + c7 + j][b4] + bf2f(gxo[j]);
        float i_ = fminf(fmaxf(0.2f * gi + 0.5f, 0.f), 1.f);
        float f_ = fminf(fmaxf(0.2f * gf + 0.5f, 0.f), 1.f);
        float g_ = fminf(fmaxf(gg, -1.f), 1.f);
        float o_ = fminf(fmaxf(0.2f * go + 0.5f, 0.f), 1.f);
        float cc = f_ * ca[j] + i_ * g_;
        ca[j] = cc;
        hv[j] = o_ * fminf(fmaxf(cc, -1.f), 1.f);
        pk.s[j] = f2bf(hv[j]);
      }
      size_t qi = (((size_t)((p ^ 1) * 2 + dir) * 32 + b4) * 1024 + col0) >> 2;
      __hip_atomic_store((unsigned long long*)hbuf + qi, pk.u,
                         __ATOMIC_RELAXED, __HIP_MEMORY_SCOPE_AGENT);
      size_t yi = ((size_t)(t * 32 + b4)) * 2048 + dir * 1024 + col0;
      if (LAST) {
        float4 f4; f4.x = hv[0]; f4.y = hv[1]; f4.z = hv[2]; f4.w = hv[3];
        *(float4*)((float*)yout + yi) = f4;
      } else {
        short4v ys; ys.x = pk.s[0]; ys.y = pk.s[1]; ys.z = pk.s[2]; ys.w = pk.s[3];
        *(short4v*)((short*)yout + yi) = ys;
      }
    }

    xbar(ctr, 128 * (ts + 2), tid);
    p ^= 1;
  }
}

// ---------------- host ----------------
extern "C" void kernel_launch(void* const* d_in, const int* in_sizes, int n_in,
                              void* d_out, int out_size, void* d_ws, size_t ws_size,
                              hipStream_t stream)
{
  const float* x  = (const float*)d_in[0];
  const float* h0 = (const float*)d_in[1];
  const float* c0 = (const float*)d_in[2];
  auto W = [&](int l, int d, int k) { return (const float*)d_in[3 + l * 8 + d * 4 + k]; };
  // k: 0=w_ih, 1=w_hh, 2=b_ih, 3=b_hh

  char* base = (char*)d_ws;
  size_t off = 0;
  auto alloc = [&](size_t bytes) {
    void* p = base + off;
    off = (off + bytes + 255) & ~(size_t)255;
    return p;
  };
  short* xb    = (short*)alloc(16384ull * 320 * 2);
  short* wih0  = (short*)alloc(8192ull * 320 * 2);
  short* wih1  = (short*)alloc(8192ull * 2048 * 2);
  short* wih2  = (short*)alloc(8192ull * 2048 * 2);
  short* whh0  = (short*)alloc(8192ull * 1024 * 2);
  short* whh1  = (short*)alloc(8192ull * 1024 * 2);
  short* whh2  = (short*)alloc(8192ull * 1024 * 2);
  float* bias0 = (float*)alloc(8192ull * 4);
  float* bias1 = (float*)alloc(8192ull * 4);
  float* bias2 = (float*)alloc(8192ull * 4);
  short* gx    = (short*)alloc(16384ull * 8192 * 2);
  short* y1    = (short*)alloc(16384ull * 2048 * 2);
  short* y2    = (short*)alloc(16384ull * 2048 * 2);
  short* hbuf  = (short*)alloc(2ull * 2 * 32 * 1024 * 2);
  int*   bar   = (int*)alloc(512);
  (void)ws_size; (void)in_sizes; (void)n_in; (void)out_size;

  auto cvt = [&](const float* s, short* d, size_t n) {
    size_t want = (n / 4 + 255) / 256;
    int blocks = (int)(want > 2048 ? 2048 : want);
    k_cvt<<<dim3(blocks), dim3(256), 0, stream>>>(s, d, (int)n);
  };

  cvt(x, xb, 16384ull * 320);
  short* wihs[3] = { wih0, wih1, wih2 };
  short* whhs[3] = { whh0, whh1, whh2 };
  float* biases[3] = { bias0, bias1, bias2 };
  for (int l = 0; l < 3; ++l) {
    size_t kin = (l == 0) ? 320 : 2048;
    cvt(W(l, 0, 0), wihs[l],                  4096 * kin);
    cvt(W(l, 1, 0), wihs[l] + 4096 * kin,     4096 * kin);
    cvt(W(l, 0, 1), whhs[l],                  4096ull * 1024);
    cvt(W(l, 1, 1), whhs[l] + 4096ull * 1024, 4096ull * 1024);
    k_bias<<<dim3(32), dim3(256), 0, stream>>>(W(l, 0, 2), W(l, 0, 3), W(l, 1, 2), W(l, 1, 3), biases[l]);
  }

  const int M = 16384, N = 8192;

  // ---- layer 0 ----
  k_gemm<<<dim3((M / 128) * (N / 128)), dim3(256), 0, stream>>>(xb, wih0, bias0, gx, M, N, 320);
  k_zero<<<dim3(1), dim3(2), 0, stream>>>(bar);
  {
    const short* gxc = gx; const short* whhc = whh0; short* hb = hbuf;
    void* yo = (void*)y1; int layer = 0;
    void* args[] = { &gxc, &whhc, &h0, &c0, &hb, &yo, &layer, &bar };
    hipLaunchCooperativeKernel(k_scan<false>, dim3(256), dim3(256), args, 0, stream);
  }
  // ---- layer 1 ----
  k_gemm<<<dim3((M / 128) * (N / 128)), dim3(256), 0, stream>>>(y1, wih1, bias1, gx, M, N, 2048);
  k_zero<<<dim3(1), dim3(2), 0, stream>>>(bar);
  {
    const short* gxc = gx; const short* whhc = whh1; short* hb = hbuf;
    void* yo = (void*)y2; int layer = 1;
    void* args[] = { &gxc, &whhc, &h0, &c0, &hb, &yo, &layer, &bar };
    hipLaunchCooperativeKernel(k_scan<false>, dim3(256), dim3(256), args, 0, stream);
  }
  // ---- layer 2 ----
  k_gemm<<<dim3((M / 128) * (N / 128)), dim3(256), 0, stream>>>(y2, wih2, bias2, gx, M, N, 2048);
  k_zero<<<dim3(1), dim3(2), 0, stream>>>(bar);
  {
    const short* gxc = gx; const short* whhc = whh2; short* hb = hbuf;
    void* yo = d_out; int layer = 2;
    void* args[] = { &gxc, &whhc, &h0, &c0, &hb, &yo, &layer, &bar };
    hipLaunchCooperativeKernel(k_scan<true>, dim3(256), dim3(256), args, 0, stream);
  }
}

// Round 3
// 20768.640 us; speedup vs baseline: 5.0213x; 1.1758x over previous
//
#include <hip/hip_runtime.h>

typedef __attribute__((ext_vector_type(8))) short short8;
typedef __attribute__((ext_vector_type(4))) short short4v;
typedef __attribute__((ext_vector_type(4))) float f32x4;

__device__ __forceinline__ short f2bf(float x) {
  union { float f; unsigned u; } v; v.f = x;
  unsigned r = v.u + 0x7fffu + ((v.u >> 16) & 1u);   // RNE
  return (short)(r >> 16);
}
__device__ __forceinline__ float bf2f(short b) {
  union { unsigned u; float f; } v; v.u = ((unsigned)(unsigned short)b) << 16;
  return v.f;
}

#define GLOAD_LDS16(g, l) __builtin_amdgcn_global_load_lds( \
    (const __attribute__((address_space(1))) void*)(g),     \
    (__attribute__((address_space(3))) void*)(l), 16, 0, 0)

// ---------------- f32 -> bf16 conversion ----------------
__global__ void k_cvt(const float* __restrict__ s, short* __restrict__ d, int n) {
  int stride = gridDim.x * blockDim.x * 4;
  for (int i = (blockIdx.x * blockDim.x + threadIdx.x) * 4; i < n; i += stride) {
    float4 v = *(const float4*)(s + i);
    short4v o;
    o.x = f2bf(v.x); o.y = f2bf(v.y); o.z = f2bf(v.z); o.w = f2bf(v.w);
    *(short4v*)(d + i) = o;
  }
}

// ---------------- combined bias (fwd 0:4096, rev 4096:8192) ----------------
__global__ void k_bias(const float* __restrict__ bif, const float* __restrict__ bhf,
                       const float* __restrict__ bir, const float* __restrict__ bhr,
                       float* __restrict__ o) {
  int i = blockIdx.x * 256 + threadIdx.x;
  o[i] = (i < 4096) ? (bif[i] + bhf[i]) : (bir[i - 4096] + bhr[i - 4096]);
}

// ---------------- zero the barrier block (8KB) ----------------
__global__ void k_zero(int* __restrict__ p) {
  p[threadIdx.x] = 0; p[threadIdx.x + 1024] = 0;
}

// ---------------- input GEMM: C[M][N] = A[M][K] * Bt[N][K]^T + bias, bf16 out ----
__global__ void __launch_bounds__(256) k_gemm(
    const short* __restrict__ A, const short* __restrict__ Bt,
    const float* __restrict__ bias, short* __restrict__ C,
    int M, int N, int K)
{
  __shared__ short Al[128 * 64];
  __shared__ short Bl[128 * 64];
  const int nm = M >> 7;
  int wg = blockIdx.x;
  int q = gridDim.x >> 3;                   // gridDim.x % 8 == 0 (8192)
  wg = (wg & 7) * q + (wg >> 3);            // XCD-aware swizzle (bijective)
  const int mt = wg % nm, nt = wg / nm;
  const int tid = threadIdx.x, lane = tid & 63, w = tid >> 6;
  const int wr = w >> 1, wc = w & 1;
  const short* Ab = A + (size_t)(mt * 128) * K;
  const short* Bb = Bt + (size_t)(nt * 128) * K;
  f32x4 acc[4][4] = {};
  const int lrow = lane >> 3, lseg = lane & 7;

  for (int kt = 0; kt < K; kt += 64) {
#pragma unroll
    for (int s = 0; s < 4; ++s) {
      int chunk = s * 4 + w;                // wave-uniform LDS base
      int r = chunk * 8 + lrow;
      GLOAD_LDS16(Ab + (size_t)r * K + kt + lseg * 8, &Al[chunk * 512]);
      GLOAD_LDS16(Bb + (size_t)r * K + kt + lseg * 8, &Bl[chunk * 512]);
    }
    __syncthreads();
#pragma unroll
    for (int kk = 0; kk < 2; ++kk) {
      short8 af[4], bfr[4];
#pragma unroll
      for (int i = 0; i < 4; ++i) {
        af[i]  = *(const short8*)&Al[(wr * 64 + i * 16 + (lane & 15)) * 64 + kk * 32 + (lane >> 4) * 8];
        bfr[i] = *(const short8*)&Bl[(wc * 64 + i * 16 + (lane & 15)) * 64 + kk * 32 + (lane >> 4) * 8];
      }
#pragma unroll
      for (int i = 0; i < 4; ++i)
#pragma unroll
        for (int j = 0; j < 4; ++j)
          acc[i][j] = __builtin_amdgcn_mfma_f32_16x16x32_bf16(af[i], bfr[j], acc[i][j], 0, 0, 0);
    }
    __syncthreads();
  }

  const int r0 = mt * 128 + wr * 64, c0n = nt * 128 + wc * 64;
#pragma unroll
  for (int i = 0; i < 4; ++i) {
#pragma unroll
    for (int j = 0; j < 4; ++j) {
      int col = c0n + j * 16 + (lane & 15);
      float bv = bias[col];
#pragma unroll
      for (int r = 0; r < 4; ++r) {
        int row = r0 + i * 16 + (lane >> 4) * 4 + r;
        C[(size_t)row * N + col] = f2bf(acc[i][j][r] + bv);
      }
    }
  }
}

// ---------------- tree barrier without L2 writeback ----------------
// bar layout (128B lines = 32 ints):
//   lines  0..15 : release flags  flag[dir*8 + g]
//   lines 16..17 : root counters  root[dir]
//   lines 18..33 : lvl1 counters  lvl1[dir*8 + g]
// All cross-WG data must be stored with agent-scope atomics before arrival;
// vmcnt(0) puts them at the coherence point; acquire fence (inv only, no
// writeback) drops stale clean lines before re-reading.
__device__ __forceinline__ void xbar(int* bar, int dir, int g, int ts1, int tid) {
  asm volatile("s_waitcnt vmcnt(0)" ::: "memory");
  __syncthreads();
  if (tid == 0) {
    int* l1 = bar + (18 + dir * 8 + g) * 32;
    int old = __hip_atomic_fetch_add(l1, 1, __ATOMIC_RELAXED, __HIP_MEMORY_SCOPE_AGENT);
    if (old == ts1 * 16 - 1) {
      int* rt = bar + (16 + dir) * 32;
      int ro = __hip_atomic_fetch_add(rt, 1, __ATOMIC_RELAXED, __HIP_MEMORY_SCOPE_AGENT);
      if (ro == ts1 * 8 - 1) {
#pragma unroll
        for (int k = 0; k < 8; ++k)
          __hip_atomic_store(bar + (dir * 8 + k) * 32, ts1,
                             __ATOMIC_RELAXED, __HIP_MEMORY_SCOPE_AGENT);
      }
    }
    int* fl = bar + (dir * 8 + g) * 32;
    while (__hip_atomic_load(fl, __ATOMIC_RELAXED, __HIP_MEMORY_SCOPE_AGENT) < ts1)
      __builtin_amdgcn_s_sleep(2);
  }
  __syncthreads();
  __builtin_amdgcn_fence(__ATOMIC_ACQUIRE, "agent");
}

// ---------------- persistent bidirectional scan ----------------
// 256 WGs x 256 threads. WG = (dir = blk>>7, wid = blk&127) owns h-cols [wid*8, wid*8+8).
// W_hh fragments pinned in registers; h double-buffered bf16 in global, published
// via agent-scope atomic stores; per-direction tree barrier.
template <bool LAST>
__global__ void __launch_bounds__(256, 1) k_scan(
    const short* __restrict__ gx,     // [16384][8192] bf16 (bias included)
    const short* __restrict__ whh,    // [8192][1024] bf16 (fwd rows 0:4096, rev 4096:8192)
    const float* __restrict__ h0,     // [6][32][1024]
    const float* __restrict__ c0,
    short* __restrict__ hbuf,         // [2 parity][2 dir][32][1024] bf16
    void* __restrict__ yout,          // bf16 [512][32][2048] or f32 (LAST)
    int layer, int* __restrict__ bar)
{
  const int tid = threadIdx.x, lane = tid & 63, w = tid >> 6;
  const int dir = blockIdx.x >> 7, wid = blockIdx.x & 127;
  const int grp = wid >> 4;
  const int hc0 = wid * 8;
  const int m = w & 1, n = w >> 1;          // wave quadrant of the 32x32 gate tile
  __shared__ float gateL[32][33];

  // --- weights into registers: lane holds B-frag (col = local gate row, 8 k per ks) ---
  short8 wf[32];
  {
    const int lcol = n * 16 + (lane & 15);                       // 0..31: [i f g o] x 8 cols
    const int grow = dir * 4096 + (lcol >> 3) * 1024 + hc0 + (lcol & 7);
    const short* wp = whh + (size_t)grow * 1024 + (lane >> 4) * 8;
#pragma unroll
    for (int ks = 0; ks < 32; ++ks) wf[ks] = *(const short8*)(wp + ks * 32);
  }
  // Pin wf: opaque asm def prevents the compiler from rematerializing the
  // loop-invariant weight loads inside the step loop (r2: VGPR_Count=96
  // proved wf was being re-read from L2 every step).
#pragma unroll
  for (int ks = 0; ks < 32; ++ks) asm volatile("" : "+v"(wf[ks]));

  // --- state init: 64 active threads, each owns (batch b, 4 h-cols) ---
  const int b4 = tid >> 1, cg = tid & 1, col0 = hc0 + cg * 4;
  float ca[4] = {0.f, 0.f, 0.f, 0.f};
  short4v pgi, pgf, pgg, pgo;               // prefetched gx for the upcoming step
  if (tid < 64) {
    const int sidx = ((2 * layer + dir) * 32 + b4) * 1024 + col0;
    float4 cv = *(const float4*)(c0 + sidx);
    ca[0] = cv.x; ca[1] = cv.y; ca[2] = cv.z; ca[3] = cv.w;
    float4 hv = *(const float4*)(h0 + sidx);
    union { unsigned long long u; short s[4]; } pk;
    pk.s[0] = f2bf(hv.x); pk.s[1] = f2bf(hv.y); pk.s[2] = f2bf(hv.z); pk.s[3] = f2bf(hv.w);
    size_t qi = (((size_t)dir * 32 + b4) * 1024 + col0) >> 2;    // parity 0
    __hip_atomic_store((unsigned long long*)hbuf + qi, pk.u,
                       __ATOMIC_RELAXED, __HIP_MEMORY_SCOPE_AGENT);
    const int t0 = dir ? 511 : 0;
    const short* gp = gx + ((size_t)(t0 * 32 + b4)) * 8192 + dir * 4096 + col0;
    pgi = *(const short4v*)(gp);
    pgf = *(const short4v*)(gp + 1024);
    pgg = *(const short4v*)(gp + 2048);
    pgo = *(const short4v*)(gp + 3072);
  }
  const int ab = m * 16 + (lane & 15);      // batch row for A-fragments

  xbar(bar, dir, grp, 1, tid);

  int p = 0;
  for (int ts = 0; ts < 512; ++ts) {
    const int t = dir ? (511 - ts) : ts;

    // --- gates = h @ Whh^T via MFMA; A-frags from global (L2/L3, post-inv) ---
    const short* ap = hbuf + ((size_t)(p * 2 + dir) * 32 + ab) * 1024 + (lane >> 4) * 8;
    short8 af[32];
#pragma unroll
    for (int ks = 0; ks < 32; ++ks) af[ks] = *(const short8*)(ap + ks * 32);
    f32x4 acc0 = {}, acc1 = {}, acc2 = {}, acc3 = {};
#pragma unroll
    for (int ks = 0; ks < 32; ks += 4) {
      acc0 = __builtin_amdgcn_mfma_f32_16x16x32_bf16(af[ks],     wf[ks],     acc0, 0, 0, 0);
      acc1 = __builtin_amdgcn_mfma_f32_16x16x32_bf16(af[ks + 1], wf[ks + 1], acc1, 0, 0, 0);
      acc2 = __builtin_amdgcn_mfma_f32_16x16x32_bf16(af[ks + 2], wf[ks + 2], acc2, 0, 0, 0);
      acc3 = __builtin_amdgcn_mfma_f32_16x16x32_bf16(af[ks + 3], wf[ks + 3], acc3, 0, 0, 0);
    }
    f32x4 acc = (acc0 + acc1) + (acc2 + acc3);
#pragma unroll
    for (int r = 0; r < 4; ++r)
      gateL[n * 16 + (lane & 15)][m * 16 + (lane >> 4) * 4 + r] = acc[r];
    __syncthreads();

    // --- elementwise update: thread (tid<64) owns (b=b4, cols col0..col0+3) ---
    if (tid < 64) {
      const int c7 = cg * 4;
      float hv[4];
      union { unsigned long long u; short s[4]; } pk;
#pragma unroll
      for (int j = 0; j < 4; ++j) {
        float gi = gateL[c7 + j][b4]      + bf2f(pgi[j]);
        float gf = gateL[8 + c7 + j][b4]  + bf2f(pgf[j]);
        float gg = gateL[16 + c7 + j][b4] + bf2f(pgg[j]);
        float go = gateL[24 + c7 + j][b4] + bf2f(pgo[j]);
        float i_ = fminf(fmaxf(0.2f * gi + 0.5f, 0.f), 1.f);
        float f_ = fminf(fmaxf(0.2f * gf + 0.5f, 0.f), 1.f);
        float g_ = fminf(fmaxf(gg, -1.f), 1.f);
        float o_ = fminf(fmaxf(0.2f * go + 0.5f, 0.f), 1.f);
        float cc = f_ * ca[j] + i_ * g_;
        ca[j] = cc;
        hv[j] = o_ * fminf(fmaxf(cc, -1.f), 1.f);
        pk.s[j] = f2bf(hv[j]);
      }
      // prefetch next step's gx (completes during the barrier spin)
      {
        const int tsn = (ts < 511) ? ts + 1 : ts;
        const int tn = dir ? (511 - tsn) : tsn;
        const short* gp = gx + ((size_t)(tn * 32 + b4)) * 8192 + dir * 4096 + col0;
        pgi = *(const short4v*)(gp);
        pgf = *(const short4v*)(gp + 1024);
        pgg = *(const short4v*)(gp + 2048);
        pgo = *(const short4v*)(gp + 3072);
      }
      size_t qi = (((size_t)((p ^ 1) * 2 + dir) * 32 + b4) * 1024 + col0) >> 2;
      __hip_atomic_store((unsigned long long*)hbuf + qi, pk.u,
                         __ATOMIC_RELAXED, __HIP_MEMORY_SCOPE_AGENT);
      size_t yi = ((size_t)(t * 32 + b4)) * 2048 + dir * 1024 + col0;
      if (LAST) {
        float4 f4; f4.x = hv[0]; f4.y = hv[1]; f4.z = hv[2]; f4.w = hv[3];
        *(float4*)((float*)yout + yi) = f4;
      } else {
        short4v ys; ys.x = pk.s[0]; ys.y = pk.s[1]; ys.z = pk.s[2]; ys.w = pk.s[3];
        *(short4v*)((short*)yout + yi) = ys;
      }
    }

    xbar(bar, dir, grp, ts + 2, tid);
    p ^= 1;
  }
}

// ---------------- host ----------------
extern "C" void kernel_launch(void* const* d_in, const int* in_sizes, int n_in,
                              void* d_out, int out_size, void* d_ws, size_t ws_size,
                              hipStream_t stream)
{
  const float* x  = (const float*)d_in[0];
  const float* h0 = (const float*)d_in[1];
  const float* c0 = (const float*)d_in[2];
  auto W = [&](int l, int d, int k) { return (const float*)d_in[3 + l * 8 + d * 4 + k]; };
  // k: 0=w_ih, 1=w_hh, 2=b_ih, 3=b_hh

  char* base = (char*)d_ws;
  size_t off = 0;
  auto alloc = [&](size_t bytes) {
    void* p = base + off;
    off = (off + bytes + 255) & ~(size_t)255;
    return p;
  };
  short* xb    = (short*)alloc(16384ull * 320 * 2);
  short* wih0  = (short*)alloc(8192ull * 320 * 2);
  short* wih1  = (short*)alloc(8192ull * 2048 * 2);
  short* wih2  = (short*)alloc(8192ull * 2048 * 2);
  short* whh0  = (short*)alloc(8192ull * 1024 * 2);
  short* whh1  = (short*)alloc(8192ull * 1024 * 2);
  short* whh2  = (short*)alloc(8192ull * 1024 * 2);
  float* bias0 = (float*)alloc(8192ull * 4);
  float* bias1 = (float*)alloc(8192ull * 4);
  float* bias2 = (float*)alloc(8192ull * 4);
  short* gx    = (short*)alloc(16384ull * 8192 * 2);
  short* y1    = (short*)alloc(16384ull * 2048 * 2);
  short* y2    = (short*)alloc(16384ull * 2048 * 2);
  short* hbuf  = (short*)alloc(2ull * 2 * 32 * 1024 * 2);
  int*   bar   = (int*)alloc(8192);
  (void)ws_size; (void)in_sizes; (void)n_in; (void)out_size;

  auto cvt = [&](const float* s, short* d, size_t n) {
    size_t want = (n / 4 + 255) / 256;
    int blocks = (int)(want > 2048 ? 2048 : want);
    k_cvt<<<dim3(blocks), dim3(256), 0, stream>>>(s, d, (int)n);
  };

  cvt(x, xb, 16384ull * 320);
  short* wihs[3] = { wih0, wih1, wih2 };
  short* whhs[3] = { whh0, whh1, whh2 };
  float* biases[3] = { bias0, bias1, bias2 };
  for (int l = 0; l < 3; ++l) {
    size_t kin = (l == 0) ? 320 : 2048;
    cvt(W(l, 0, 0), wihs[l],                  4096 * kin);
    cvt(W(l, 1, 0), wihs[l] + 4096 * kin,     4096 * kin);
    cvt(W(l, 0, 1), whhs[l],                  4096ull * 1024);
    cvt(W(l, 1, 1), whhs[l] + 4096ull * 1024, 4096ull * 1024);
    k_bias<<<dim3(32), dim3(256), 0, stream>>>(W(l, 0, 2), W(l, 0, 3), W(l, 1, 2), W(l, 1, 3), biases[l]);
  }

  const int M = 16384, N = 8192;

  // ---- layer 0 ----
  k_gemm<<<dim3((M / 128) * (N / 128)), dim3(256), 0, stream>>>(xb, wih0, bias0, gx, M, N, 320);
  k_zero<<<dim3(1), dim3(1024), 0, stream>>>(bar);
  {
    const short* gxc = gx; const short* whhc = whh0; short* hb = hbuf;
    void* yo = (void*)y1; int layer = 0;
    void* args[] = { &gxc, &whhc, &h0, &c0, &hb, &yo, &layer, &bar };
    hipLaunchCooperativeKernel(k_scan<false>, dim3(256), dim3(256), args, 0, stream);
  }
  // ---- layer 1 ----
  k_gemm<<<dim3((M / 128) * (N / 128)), dim3(256), 0, stream>>>(y1, wih1, bias1, gx, M, N, 2048);
  k_zero<<<dim3(1), dim3(1024), 0, stream>>>(bar);
  {
    const short* gxc = gx; const short* whhc = whh1; short* hb = hbuf;
    void* yo = (void*)y2; int layer = 1;
    void* args[] = { &gxc, &whhc, &h0, &c0, &hb, &yo, &layer, &bar };
    hipLaunchCooperativeKernel(k_scan<false>, dim3(256), dim3(256), args, 0, stream);
  }
  // ---- layer 2 ----
  k_gemm<<<dim3((M / 128) * (N / 128)), dim3(256), 0, stream>>>(y2, wih2, bias2, gx, M, N, 2048);
  k_zero<<<dim3(1), dim3(1024), 0, stream>>>(bar);
  {
    const short* gxc = gx; const short* whhc = whh2; short* hb = hbuf;
    void* yo = d_out; int layer = 2;
    void* args[] = { &gxc, &whhc, &h0, &c0, &hb, &yo, &layer, &bar };
    hipLaunchCooperativeKernel(k_scan<true>, dim3(256), dim3(256), args, 0, stream);
  }
}

// Round 4
// 17098.784 us; speedup vs baseline: 6.0991x; 1.2146x over previous
//
#include <hip/hip_runtime.h>

typedef __attribute__((ext_vector_type(8))) short short8;
typedef __attribute__((ext_vector_type(4))) short short4v;
typedef __attribute__((ext_vector_type(4))) float f32x4;

__device__ __forceinline__ short f2bf(float x) {
  union { float f; unsigned u; } v; v.f = x;
  unsigned r = v.u + 0x7fffu + ((v.u >> 16) & 1u);   // RNE
  return (short)(r >> 16);
}
__device__ __forceinline__ float bf2f(short b) {
  union { unsigned u; float f; } v; v.u = ((unsigned)(unsigned short)b) << 16;
  return v.f;
}

#define GLOAD_LDS16(g, l) __builtin_amdgcn_global_load_lds( \
    (const __attribute__((address_space(1))) void*)(g),     \
    (__attribute__((address_space(3))) void*)(l), 16, 0, 0)

// ---------------- f32 -> bf16 conversion ----------------
__global__ void k_cvt(const float* __restrict__ s, short* __restrict__ d, int n) {
  int stride = gridDim.x * blockDim.x * 4;
  for (int i = (blockIdx.x * blockDim.x + threadIdx.x) * 4; i < n; i += stride) {
    float4 v = *(const float4*)(s + i);
    short4v o;
    o.x = f2bf(v.x); o.y = f2bf(v.y); o.z = f2bf(v.z); o.w = f2bf(v.w);
    *(short4v*)(d + i) = o;
  }
}

// ---------------- combined bias (fwd 0:4096, rev 4096:8192) ----------------
__global__ void k_bias(const float* __restrict__ bif, const float* __restrict__ bhf,
                       const float* __restrict__ bir, const float* __restrict__ bhr,
                       float* __restrict__ o) {
  int i = blockIdx.x * 256 + threadIdx.x;
  o[i] = (i < 4096) ? (bif[i] + bhf[i]) : (bir[i - 4096] + bhr[i - 4096]);
}

// ---------------- zero the seq block (32KB) ----------------
__global__ void k_zero(int* __restrict__ p) { p[blockIdx.x * 256 + threadIdx.x] = 0; }

// ---------------- input GEMM: C[M][N] = A[M][K] * Bt[N][K]^T + bias, bf16 out ----
__global__ void __launch_bounds__(256) k_gemm(
    const short* __restrict__ A, const short* __restrict__ Bt,
    const float* __restrict__ bias, short* __restrict__ C,
    int M, int N, int K)
{
  __shared__ short Al[128 * 64];
  __shared__ short Bl[128 * 64];
  const int nm = M >> 7;
  int wg = blockIdx.x;
  int q = gridDim.x >> 3;                   // gridDim.x % 8 == 0 (8192)
  wg = (wg & 7) * q + (wg >> 3);            // XCD-aware swizzle (bijective)
  const int mt = wg % nm, nt = wg / nm;
  const int tid = threadIdx.x, lane = tid & 63, w = tid >> 6;
  const int wr = w >> 1, wc = w & 1;
  const short* Ab = A + (size_t)(mt * 128) * K;
  const short* Bb = Bt + (size_t)(nt * 128) * K;
  f32x4 acc[4][4] = {};
  const int lrow = lane >> 3, lseg = lane & 7;

  for (int kt = 0; kt < K; kt += 64) {
#pragma unroll
    for (int s = 0; s < 4; ++s) {
      int chunk = s * 4 + w;                // wave-uniform LDS base
      int r = chunk * 8 + lrow;
      GLOAD_LDS16(Ab + (size_t)r * K + kt + lseg * 8, &Al[chunk * 512]);
      GLOAD_LDS16(Bb + (size_t)r * K + kt + lseg * 8, &Bl[chunk * 512]);
    }
    __syncthreads();
#pragma unroll
    for (int kk = 0; kk < 2; ++kk) {
      short8 af[4], bfr[4];
#pragma unroll
      for (int i = 0; i < 4; ++i) {
        af[i]  = *(const short8*)&Al[(wr * 64 + i * 16 + (lane & 15)) * 64 + kk * 32 + (lane >> 4) * 8];
        bfr[i] = *(const short8*)&Bl[(wc * 64 + i * 16 + (lane & 15)) * 64 + kk * 32 + (lane >> 4) * 8];
      }
#pragma unroll
      for (int i = 0; i < 4; ++i)
#pragma unroll
        for (int j = 0; j < 4; ++j)
          acc[i][j] = __builtin_amdgcn_mfma_f32_16x16x32_bf16(af[i], bfr[j], acc[i][j], 0, 0, 0);
    }
    __syncthreads();
  }

  const int r0 = mt * 128 + wr * 64, c0n = nt * 128 + wc * 64;
#pragma unroll
  for (int i = 0; i < 4; ++i) {
#pragma unroll
    for (int j = 0; j < 4; ++j) {
      int col = c0n + j * 16 + (lane & 15);
      float bv = bias[col];
#pragma unroll
      for (int r = 0; r < 4; ++r) {
        int row = r0 + i * 16 + (lane >> 4) * 4 + r;
        C[(size_t)row * N + col] = f2bf(acc[i][j][r] + bv);
      }
    }
  }
}

// ---------------- wait until all 128 producer seq words reach target ----------
// seqbase: [128] ints at 32-int (128B) stride. 2 slots per lane; re-poll
// laggards only. No fences: h reads after this are coherence-point loads.
__device__ __forceinline__ void seqwait(int* seqbase, int target, int lane) {
  int* p0 = seqbase + (lane * 2) * 32;
  int* p1 = p0 + 32;
  int d0 = 0, d1 = 0;
  while (true) {
    if (!d0) d0 = (__hip_atomic_load(p0, __ATOMIC_RELAXED, __HIP_MEMORY_SCOPE_AGENT) >= target);
    if (!d1) d1 = (__hip_atomic_load(p1, __ATOMIC_RELAXED, __HIP_MEMORY_SCOPE_AGENT) >= target);
    if (__all(d0 & d1)) break;
    __builtin_amdgcn_s_sleep(1);
  }
  asm volatile("" ::: "memory");
}

// ---------------- persistent bidirectional scan ----------------
// 256 WGs x 256 threads. WG = (dir = blk>>7, wid = blk&127) owns h-cols [wid*8, wid*8+8).
// Publication protocol: producer stores h slice (agent atomics), vmcnt(0), then
// seq[wid] = ts+2. Consumer: all seq >= ts+1  <=>  h[ts-1] fully visible AND
// everyone is done reading the parity this step will overwrite (skew <= 1).
// h reads are 8B agent-scope atomic loads (coherence point, no cache inv).
template <bool LAST>
__global__ void __launch_bounds__(256, 1) k_scan(
    const short* __restrict__ gx,     // [16384][8192] bf16 (bias included)
    const short* __restrict__ whh,    // [8192][1024] bf16 (fwd rows 0:4096, rev 4096:8192)
    const float* __restrict__ h0,     // [6][32][1024]
    const float* __restrict__ c0,
    short* __restrict__ hbuf,         // [2 parity][2 dir][32][1024] bf16
    void* __restrict__ yout,          // bf16 [512][32][2048] or f32 (LAST)
    int layer, int* __restrict__ bar) // seq: [2 dir][128] ints @ 32-int stride
{
  const int tid = threadIdx.x, lane = tid & 63, w = tid >> 6;
  const int dir = blockIdx.x >> 7, wid = blockIdx.x & 127;
  const int hc0 = wid * 8;
  const int m = w & 1, n = w >> 1;          // wave quadrant of the 32x32 gate tile
  __shared__ float gateL[32][33];
  int* seq = bar + dir * 128 * 32;

  // --- weights into registers: lane holds B-frag (col = local gate row, 8 k per ks) ---
  short8 wf[32];
  {
    const int lcol = n * 16 + (lane & 15);                       // 0..31: [i f g o] x 8 cols
    const int grow = dir * 4096 + (lcol >> 3) * 1024 + hc0 + (lcol & 7);
    const short* wp = whh + (size_t)grow * 1024 + (lane >> 4) * 8;
#pragma unroll
    for (int ks = 0; ks < 32; ++ks) wf[ks] = *(const short8*)(wp + ks * 32);
  }
#pragma unroll
  for (int ks = 0; ks < 32; ++ks) asm volatile("" : "+v"(wf[ks]));

  // --- state init: 64 active threads, each owns (batch b, 4 h-cols) ---
  const int b4 = tid >> 1, cg = tid & 1, col0 = hc0 + cg * 4;
  float ca[4] = {0.f, 0.f, 0.f, 0.f};
  short4v pgi, pgf, pgg, pgo;               // prefetched gx for the upcoming step
  if (tid < 64) {
    const int sidx = ((2 * layer + dir) * 32 + b4) * 1024 + col0;
    float4 cv = *(const float4*)(c0 + sidx);
    ca[0] = cv.x; ca[1] = cv.y; ca[2] = cv.z; ca[3] = cv.w;
    float4 hv = *(const float4*)(h0 + sidx);
    union { unsigned long long u; short s[4]; } pk;
    pk.s[0] = f2bf(hv.x); pk.s[1] = f2bf(hv.y); pk.s[2] = f2bf(hv.z); pk.s[3] = f2bf(hv.w);
    size_t qi = (((size_t)dir * 32 + b4) * 1024 + col0) >> 2;    // parity 0
    __hip_atomic_store((unsigned long long*)hbuf + qi, pk.u,
                       __ATOMIC_RELAXED, __HIP_MEMORY_SCOPE_AGENT);
    asm volatile("s_waitcnt vmcnt(0)" ::: "memory");             // wave0 stores acked
  }
  if (tid == 0)
    __hip_atomic_store(seq + wid * 32, 1, __ATOMIC_RELAXED, __HIP_MEMORY_SCOPE_AGENT);
  if (tid < 64) {
    const int t0 = dir ? 511 : 0;
    const short* gp = gx + ((size_t)(t0 * 32 + b4)) * 8192 + dir * 4096 + col0;
    pgi = *(const short4v*)(gp);
    pgf = *(const short4v*)(gp + 1024);
    pgg = *(const short4v*)(gp + 2048);
    pgo = *(const short4v*)(gp + 3072);
  }
  const int ab = m * 16 + (lane & 15);      // batch row for A-fragments

  int p = 0;
  for (int ts = 0; ts < 512; ++ts) {
    const int t = dir ? (511 - ts) : ts;

    seqwait(seq, ts + 1, lane);

    // --- gates = h @ Whh^T via MFMA; h via coherence-point 8B atomic loads ---
    unsigned long long* ap = (unsigned long long*)
        (hbuf + ((size_t)(p * 2 + dir) * 32 + ab) * 1024) + (lane >> 4) * 2;
    short8 af[32];
#pragma unroll
    for (int ks = 0; ks < 32; ++ks) {
      union { unsigned long long u[2]; short8 v; } tu;
      tu.u[0] = __hip_atomic_load(ap + ks * 8,     __ATOMIC_RELAXED, __HIP_MEMORY_SCOPE_AGENT);
      tu.u[1] = __hip_atomic_load(ap + ks * 8 + 1, __ATOMIC_RELAXED, __HIP_MEMORY_SCOPE_AGENT);
      af[ks] = tu.v;
    }
    f32x4 acc0 = {}, acc1 = {}, acc2 = {}, acc3 = {};
#pragma unroll
    for (int ks = 0; ks < 32; ks += 4) {
      acc0 = __builtin_amdgcn_mfma_f32_16x16x32_bf16(af[ks],     wf[ks],     acc0, 0, 0, 0);
      acc1 = __builtin_amdgcn_mfma_f32_16x16x32_bf16(af[ks + 1], wf[ks + 1], acc1, 0, 0, 0);
      acc2 = __builtin_amdgcn_mfma_f32_16x16x32_bf16(af[ks + 2], wf[ks + 2], acc2, 0, 0, 0);
      acc3 = __builtin_amdgcn_mfma_f32_16x16x32_bf16(af[ks + 3], wf[ks + 3], acc3, 0, 0, 0);
    }
    f32x4 acc = (acc0 + acc1) + (acc2 + acc3);
#pragma unroll
    for (int r = 0; r < 4; ++r)
      gateL[n * 16 + (lane & 15)][m * 16 + (lane >> 4) * 4 + r] = acc[r];
    __syncthreads();

    // --- elementwise update: thread (tid<64) owns (b=b4, cols col0..col0+3) ---
    if (tid < 64) {
      const int c7 = cg * 4;
      float hv[4];
      union { unsigned long long u; short s[4]; } pk;
#pragma unroll
      for (int j = 0; j < 4; ++j) {
        float gi = gateL[c7 + j][b4]      + bf2f(pgi[j]);
        float gf = gateL[8 + c7 + j][b4]  + bf2f(pgf[j]);
        float gg = gateL[16 + c7 + j][b4] + bf2f(pgg[j]);
        float go = gateL[24 + c7 + j][b4] + bf2f(pgo[j]);
        float i_ = fminf(fmaxf(0.2f * gi + 0.5f, 0.f), 1.f);
        float f_ = fminf(fmaxf(0.2f * gf + 0.5f, 0.f), 1.f);
        float g_ = fminf(fmaxf(gg, -1.f), 1.f);
        float o_ = fminf(fmaxf(0.2f * go + 0.5f, 0.f), 1.f);
        float cc = f_ * ca[j] + i_ * g_;
        ca[j] = cc;
        hv[j] = o_ * fminf(fmaxf(cc, -1.f), 1.f);
        pk.s[j] = f2bf(hv[j]);
      }
      size_t qi = (((size_t)((p ^ 1) * 2 + dir) * 32 + b4) * 1024 + col0) >> 2;
      __hip_atomic_store((unsigned long long*)hbuf + qi, pk.u,
                         __ATOMIC_RELAXED, __HIP_MEMORY_SCOPE_AGENT);
      size_t yi = ((size_t)(t * 32 + b4)) * 2048 + dir * 1024 + col0;
      if (LAST) {
        float4 f4; f4.x = hv[0]; f4.y = hv[1]; f4.z = hv[2]; f4.w = hv[3];
        *(float4*)((float*)yout + yi) = f4;
      } else {
        short4v ys; ys.x = pk.s[0]; ys.y = pk.s[1]; ys.z = pk.s[2]; ys.w = pk.s[3];
        *(short4v*)((short*)yout + yi) = ys;
      }
      asm volatile("s_waitcnt vmcnt(0)" ::: "memory");   // h (+y) stores acked
    }
    if (tid == 0)
      __hip_atomic_store(seq + wid * 32, ts + 2, __ATOMIC_RELAXED, __HIP_MEMORY_SCOPE_AGENT);
    if (tid < 64 && ts < 511) {
      // prefetch next step's gx (completes during next seqwait)
      const int tn = dir ? (511 - (ts + 1)) : (ts + 1);
      const short* gp = gx + ((size_t)(tn * 32 + b4)) * 8192 + dir * 4096 + col0;
      pgi = *(const short4v*)(gp);
      pgf = *(const short4v*)(gp + 1024);
      pgg = *(const short4v*)(gp + 2048);
      pgo = *(const short4v*)(gp + 3072);
    }
    p ^= 1;
  }
}

// ---------------- host ----------------
extern "C" void kernel_launch(void* const* d_in, const int* in_sizes, int n_in,
                              void* d_out, int out_size, void* d_ws, size_t ws_size,
                              hipStream_t stream)
{
  const float* x  = (const float*)d_in[0];
  const float* h0 = (const float*)d_in[1];
  const float* c0 = (const float*)d_in[2];
  auto W = [&](int l, int d, int k) { return (const float*)d_in[3 + l * 8 + d * 4 + k]; };
  // k: 0=w_ih, 1=w_hh, 2=b_ih, 3=b_hh

  char* base = (char*)d_ws;
  size_t off = 0;
  auto alloc = [&](size_t bytes) {
    void* p = base + off;
    off = (off + bytes + 255) & ~(size_t)255;
    return p;
  };
  short* xb    = (short*)alloc(16384ull * 320 * 2);
  short* wih0  = (short*)alloc(8192ull * 320 * 2);
  short* wih1  = (short*)alloc(8192ull * 2048 * 2);
  short* wih2  = (short*)alloc(8192ull * 2048 * 2);
  short* whh0  = (short*)alloc(8192ull * 1024 * 2);
  short* whh1  = (short*)alloc(8192ull * 1024 * 2);
  short* whh2  = (short*)alloc(8192ull * 1024 * 2);
  float* bias0 = (float*)alloc(8192ull * 4);
  float* bias1 = (float*)alloc(8192ull * 4);
  float* bias2 = (float*)alloc(8192ull * 4);
  short* gx    = (short*)alloc(16384ull * 8192 * 2);
  short* y1    = (short*)alloc(16384ull * 2048 * 2);
  short* y2    = (short*)alloc(16384ull * 2048 * 2);
  short* hbuf  = (short*)alloc(2ull * 2 * 32 * 1024 * 2);
  int*   bar   = (int*)alloc(2ull * 128 * 32 * 4);
  (void)ws_size; (void)in_sizes; (void)n_in; (void)out_size;

  auto cvt = [&](const float* s, short* d, size_t n) {
    size_t want = (n / 4 + 255) / 256;
    int blocks = (int)(want > 2048 ? 2048 : want);
    k_cvt<<<dim3(blocks), dim3(256), 0, stream>>>(s, d, (int)n);
  };

  cvt(x, xb, 16384ull * 320);
  short* wihs[3] = { wih0, wih1, wih2 };
  short* whhs[3] = { whh0, whh1, whh2 };
  float* biases[3] = { bias0, bias1, bias2 };
  for (int l = 0; l < 3; ++l) {
    size_t kin = (l == 0) ? 320 : 2048;
    cvt(W(l, 0, 0), wihs[l],                  4096 * kin);
    cvt(W(l, 1, 0), wihs[l] + 4096 * kin,     4096 * kin);
    cvt(W(l, 0, 1), whhs[l],                  4096ull * 1024);
    cvt(W(l, 1, 1), whhs[l] + 4096ull * 1024, 4096ull * 1024);
    k_bias<<<dim3(32), dim3(256), 0, stream>>>(W(l, 0, 2), W(l, 0, 3), W(l, 1, 2), W(l, 1, 3), biases[l]);
  }

  const int M = 16384, N = 8192;

  // ---- layer 0 ----
  k_gemm<<<dim3((M / 128) * (N / 128)), dim3(256), 0, stream>>>(xb, wih0, bias0, gx, M, N, 320);
  k_zero<<<dim3(32), dim3(256), 0, stream>>>(bar);
  {
    const short* gxc = gx; const short* whhc = whh0; short* hb = hbuf;
    void* yo = (void*)y1; int layer = 0;
    void* args[] = { &gxc, &whhc, &h0, &c0, &hb, &yo, &layer, &bar };
    hipLaunchCooperativeKernel(k_scan<false>, dim3(256), dim3(256), args, 0, stream);
  }
  // ---- layer 1 ----
  k_gemm<<<dim3((M / 128) * (N / 128)), dim3(256), 0, stream>>>(y1, wih1, bias1, gx, M, N, 2048);
  k_zero<<<dim3(32), dim3(256), 0, stream>>>(bar);
  {
    const short* gxc = gx; const short* whhc = whh1; short* hb = hbuf;
    void* yo = (void*)y2; int layer = 1;
    void* args[] = { &gxc, &whhc, &h0, &c0, &hb, &yo, &layer, &bar };
    hipLaunchCooperativeKernel(k_scan<false>, dim3(256), dim3(256), args, 0, stream);
  }
  // ---- layer 2 ----
  k_gemm<<<dim3((M / 128) * (N / 128)), dim3(256), 0, stream>>>(y2, wih2, bias2, gx, M, N, 2048);
  k_zero<<<dim3(32), dim3(256), 0, stream>>>(bar);
  {
    const short* gxc = gx; const short* whhc = whh2; short* hb = hbuf;
    void* yo = d_out; int layer = 2;
    void* args[] = { &gxc, &whhc, &h0, &c0, &hb, &yo, &layer, &bar };
    hipLaunchCooperativeKernel(k_scan<true>, dim3(256), dim3(256), args, 0, stream);
  }
}

// Round 5
// 12501.810 us; speedup vs baseline: 8.3417x; 1.3677x over previous
//
#include <hip/hip_runtime.h>

typedef __attribute__((ext_vector_type(8))) short short8;
typedef __attribute__((ext_vector_type(4))) short short4v;
typedef __attribute__((ext_vector_type(4))) float f32x4;

__device__ __forceinline__ short f2bf(float x) {
  union { float f; unsigned u; } v; v.f = x;
  unsigned r = v.u + 0x7fffu + ((v.u >> 16) & 1u);   // RNE
  return (short)(r >> 16);
}
__device__ __forceinline__ float bf2f(short b) {
  union { unsigned u; float f; } v; v.u = ((unsigned)(unsigned short)b) << 16;
  return v.f;
}

#define GLOAD_LDS16(g, l) __builtin_amdgcn_global_load_lds( \
    (const __attribute__((address_space(1))) void*)(g),     \
    (__attribute__((address_space(3))) void*)(l), 16, 0, 0)

// ---------------- f32 -> bf16 conversion ----------------
__global__ void k_cvt(const float* __restrict__ s, short* __restrict__ d, int n) {
  int stride = gridDim.x * blockDim.x * 4;
  for (int i = (blockIdx.x * blockDim.x + threadIdx.x) * 4; i < n; i += stride) {
    float4 v = *(const float4*)(s + i);
    short4v o;
    o.x = f2bf(v.x); o.y = f2bf(v.y); o.z = f2bf(v.z); o.w = f2bf(v.w);
    *(short4v*)(d + i) = o;
  }
}

// ---------------- combined bias (fwd 0:4096, rev 4096:8192) ----------------
__global__ void k_bias(const float* __restrict__ bif, const float* __restrict__ bhf,
                       const float* __restrict__ bir, const float* __restrict__ bhr,
                       float* __restrict__ o) {
  int i = blockIdx.x * 256 + threadIdx.x;
  o[i] = (i < 4096) ? (bif[i] + bhf[i]) : (bir[i - 4096] + bhr[i - 4096]);
}

// ---------------- zero the seq block (32KB) ----------------
__global__ void k_zero(int* __restrict__ p) { p[blockIdx.x * 256 + threadIdx.x] = 0; }

// ---------------- input GEMM: C[M][N] = A[M][K] * Bt[N][K]^T + bias, bf16 out ----
__global__ void __launch_bounds__(256) k_gemm(
    const short* __restrict__ A, const short* __restrict__ Bt,
    const float* __restrict__ bias, short* __restrict__ C,
    int M, int N, int K)
{
  __shared__ short Al[128 * 64];
  __shared__ short Bl[128 * 64];
  const int nm = M >> 7;
  int wg = blockIdx.x;
  int q = gridDim.x >> 3;                   // gridDim.x % 8 == 0 (8192)
  wg = (wg & 7) * q + (wg >> 3);            // XCD-aware swizzle (bijective)
  const int mt = wg % nm, nt = wg / nm;
  const int tid = threadIdx.x, lane = tid & 63, w = tid >> 6;
  const int wr = w >> 1, wc = w & 1;
  const short* Ab = A + (size_t)(mt * 128) * K;
  const short* Bb = Bt + (size_t)(nt * 128) * K;
  f32x4 acc[4][4] = {};
  const int lrow = lane >> 3, lseg = lane & 7;

  for (int kt = 0; kt < K; kt += 64) {
#pragma unroll
    for (int s = 0; s < 4; ++s) {
      int chunk = s * 4 + w;                // wave-uniform LDS base
      int r = chunk * 8 + lrow;
      GLOAD_LDS16(Ab + (size_t)r * K + kt + lseg * 8, &Al[chunk * 512]);
      GLOAD_LDS16(Bb + (size_t)r * K + kt + lseg * 8, &Bl[chunk * 512]);
    }
    __syncthreads();
#pragma unroll
    for (int kk = 0; kk < 2; ++kk) {
      short8 af[4], bfr[4];
#pragma unroll
      for (int i = 0; i < 4; ++i) {
        af[i]  = *(const short8*)&Al[(wr * 64 + i * 16 + (lane & 15)) * 64 + kk * 32 + (lane >> 4) * 8];
        bfr[i] = *(const short8*)&Bl[(wc * 64 + i * 16 + (lane & 15)) * 64 + kk * 32 + (lane >> 4) * 8];
      }
#pragma unroll
      for (int i = 0; i < 4; ++i)
#pragma unroll
        for (int j = 0; j < 4; ++j)
          acc[i][j] = __builtin_amdgcn_mfma_f32_16x16x32_bf16(af[i], bfr[j], acc[i][j], 0, 0, 0);
    }
    __syncthreads();
  }

  const int r0 = mt * 128 + wr * 64, c0n = nt * 128 + wc * 64;
#pragma unroll
  for (int i = 0; i < 4; ++i) {
#pragma unroll
    for (int j = 0; j < 4; ++j) {
      int col = c0n + j * 16 + (lane & 15);
      float bv = bias[col];
#pragma unroll
      for (int r = 0; r < 4; ++r) {
        int row = r0 + i * 16 + (lane >> 4) * 4 + r;
        C[(size_t)row * N + col] = f2bf(acc[i][j][r] + bv);
      }
    }
  }
}

// ---------------- wait until all 128 producer seq words reach target ----------
__device__ __forceinline__ void seqwait(int* seqbase, int target, int lane) {
  int* p0 = seqbase + (lane * 2) * 32;
  int* p1 = p0 + 32;
  int d0 = 0, d1 = 0;
  while (true) {
    if (!d0) d0 = (__hip_atomic_load(p0, __ATOMIC_RELAXED, __HIP_MEMORY_SCOPE_AGENT) >= target);
    if (!d1) d1 = (__hip_atomic_load(p1, __ATOMIC_RELAXED, __HIP_MEMORY_SCOPE_AGENT) >= target);
    if (__all(d0 & d1)) break;
    __builtin_amdgcn_s_sleep(1);
  }
  asm volatile("" ::: "memory");
}

// ---------------- persistent bidirectional scan ----------------
// 256 WGs x 256 threads. WG = (dir = blk>>7, wid = blk&127) owns h-cols [wid*8, wid*8+8)
// == 32 gate rows (8 per gate type). K-SPLIT across waves: wave kq handles
// k in [kq*256, kq*256+256) for ALL four 16x16 quadrants; A-frags (16 x short8
// = 64 VGPR) are fully register-resident so all 32 b64 coherence-point loads
// issue in ONE batch (r4: quadrant-split needed 128 VGPR of A -> compiler
// chunk-serialized ~8 MALL latencies/step). Partials reduced via LDS.
template <bool LAST>
__global__ void __launch_bounds__(256, 1) k_scan(
    const short* __restrict__ gx,     // [16384][8192] bf16 (bias included)
    const short* __restrict__ whh,    // [8192][1024] bf16 (fwd rows 0:4096, rev 4096:8192)
    const float* __restrict__ h0,     // [6][32][1024]
    const float* __restrict__ c0,
    short* __restrict__ hbuf,         // [2 parity][2 dir][32][1024] bf16
    void* __restrict__ yout,          // bf16 [512][32][2048] or f32 (LAST)
    int layer, int* __restrict__ bar) // seq: [2 dir][128] ints @ 32-int stride
{
  const int tid = threadIdx.x, lane = tid & 63, kq = tid >> 6;   // wave = k-quarter
  const int dir = blockIdx.x >> 7, wid = blockIdx.x & 127;
  const int hc0 = wid * 8;
  __shared__ float part[4][32][33];         // [kq][gate][batch]
  int* seq = bar + dir * 128 * 32;

  // --- weights: wave kq, n-tile ni: col = ni*16+(lane&15), k = kq*256 + ks*32 + (lane>>4)*8 ---
  short8 wfr[16];
#pragma unroll
  for (int ni = 0; ni < 2; ++ni) {
    const int lcol = ni * 16 + (lane & 15);
    const int grow = dir * 4096 + (lcol >> 3) * 1024 + hc0 + (lcol & 7);
    const short* wp = whh + (size_t)grow * 1024 + kq * 256 + (lane >> 4) * 8;
#pragma unroll
    for (int ks = 0; ks < 8; ++ks) wfr[ni * 8 + ks] = *(const short8*)(wp + ks * 32);
  }
#pragma unroll
  for (int i = 0; i < 16; ++i) asm volatile("" : "+v"(wfr[i]));

  // --- state init: 64 active threads, each owns (batch b, 4 h-cols) ---
  const int b4 = tid >> 1, cg = tid & 1, col0 = hc0 + cg * 4;
  float ca[4] = {0.f, 0.f, 0.f, 0.f};
  short4v pgi, pgf, pgg, pgo;               // prefetched gx for the upcoming step
  if (tid < 64) {
    const int sidx = ((2 * layer + dir) * 32 + b4) * 1024 + col0;
    float4 cv = *(const float4*)(c0 + sidx);
    ca[0] = cv.x; ca[1] = cv.y; ca[2] = cv.z; ca[3] = cv.w;
    float4 hv = *(const float4*)(h0 + sidx);
    union { unsigned long long u; short s[4]; } pk;
    pk.s[0] = f2bf(hv.x); pk.s[1] = f2bf(hv.y); pk.s[2] = f2bf(hv.z); pk.s[3] = f2bf(hv.w);
    size_t qi = (((size_t)dir * 32 + b4) * 1024 + col0) >> 2;    // parity 0
    __hip_atomic_store((unsigned long long*)hbuf + qi, pk.u,
                       __ATOMIC_RELAXED, __HIP_MEMORY_SCOPE_AGENT);
    asm volatile("s_waitcnt vmcnt(0)" ::: "memory");             // wave0 stores acked
  }
  if (tid == 0)
    __hip_atomic_store(seq + wid * 32, 1, __ATOMIC_RELAXED, __HIP_MEMORY_SCOPE_AGENT);
  if (tid < 64) {
    const int t0 = dir ? 511 : 0;
    const short* gp = gx + ((size_t)(t0 * 32 + b4)) * 8192 + dir * 4096 + col0;
    pgi = *(const short4v*)(gp);
    pgf = *(const short4v*)(gp + 1024);
    pgg = *(const short4v*)(gp + 2048);
    pgo = *(const short4v*)(gp + 3072);
  }
  const int arow = lane & 15;               // batch row within m-tile
  const int kw = (lane >> 4) * 2;           // ull offset of lane's k-slice

  int p = 0;
  for (int ts = 0; ts < 512; ++ts) {
    const int t = dir ? (511 - ts) : ts;

    seqwait(seq, ts + 1, lane);

    // --- h A-frags: 32 independent b64 coherence-point loads, one batch ---
    unsigned long long* hb = (unsigned long long*)hbuf + (size_t)(p * 2 + dir) * 8192;
    short8 af[16];
#pragma unroll
    for (int mi = 0; mi < 2; ++mi) {
      const size_t rb = (size_t)(mi * 16 + arow) * 256 + kq * 64 + kw;
#pragma unroll
      for (int ks = 0; ks < 8; ++ks) {
        union { unsigned long long u[2]; short8 v; } tu;
        tu.u[0] = __hip_atomic_load(hb + rb + ks * 8,     __ATOMIC_RELAXED, __HIP_MEMORY_SCOPE_AGENT);
        tu.u[1] = __hip_atomic_load(hb + rb + ks * 8 + 1, __ATOMIC_RELAXED, __HIP_MEMORY_SCOPE_AGENT);
        af[mi * 8 + ks] = tu.v;
      }
    }
#pragma unroll
    for (int i = 0; i < 16; ++i) asm volatile("" : "+v"(af[i]));

    // --- partial gates for this k-quarter: all 4 quadrants ---
    f32x4 acc[2][2] = {};
#pragma unroll
    for (int ks = 0; ks < 8; ++ks) {
      acc[0][0] = __builtin_amdgcn_mfma_f32_16x16x32_bf16(af[ks],     wfr[ks],     acc[0][0], 0, 0, 0);
      acc[1][0] = __builtin_amdgcn_mfma_f32_16x16x32_bf16(af[8 + ks], wfr[ks],     acc[1][0], 0, 0, 0);
      acc[0][1] = __builtin_amdgcn_mfma_f32_16x16x32_bf16(af[ks],     wfr[8 + ks], acc[0][1], 0, 0, 0);
      acc[1][1] = __builtin_amdgcn_mfma_f32_16x16x32_bf16(af[8 + ks], wfr[8 + ks], acc[1][1], 0, 0, 0);
    }
#pragma unroll
    for (int mi = 0; mi < 2; ++mi)
#pragma unroll
      for (int ni = 0; ni < 2; ++ni)
#pragma unroll
        for (int r = 0; r < 4; ++r)
          part[kq][ni * 16 + (lane & 15)][mi * 16 + (lane >> 4) * 4 + r] = acc[mi][ni][r];
    __syncthreads();

    // --- elementwise update: thread (tid<64) owns (b=b4, cols col0..col0+3) ---
    if (tid < 64) {
      const int c7 = cg * 4;
      float hv[4];
      union { unsigned long long u; short s[4]; } pk;
#pragma unroll
      for (int j = 0; j < 4; ++j) {
        float gi = part[0][c7 + j][b4]      + part[1][c7 + j][b4]      + part[2][c7 + j][b4]      + part[3][c7 + j][b4]      + bf2f(pgi[j]);
        float gf = part[0][8 + c7 + j][b4]  + part[1][8 + c7 + j][b4]  + part[2][8 + c7 + j][b4]  + part[3][8 + c7 + j][b4]  + bf2f(pgf[j]);
        float gg = part[0][16 + c7 + j][b4] + part[1][16 + c7 + j][b4] + part[2][16 + c7 + j][b4] + part[3][16 + c7 + j][b4] + bf2f(pgg[j]);
        float go = part[0][24 + c7 + j][b4] + part[1][24 + c7 + j][b4] + part[2][24 + c7 + j][b4] + part[3][24 + c7 + j][b4] + bf2f(pgo[j]);
        float i_ = fminf(fmaxf(0.2f * gi + 0.5f, 0.f), 1.f);
        float f_ = fminf(fmaxf(0.2f * gf + 0.5f, 0.f), 1.f);
        float g_ = fminf(fmaxf(gg, -1.f), 1.f);
        float o_ = fminf(fmaxf(0.2f * go + 0.5f, 0.f), 1.f);
        float cc = f_ * ca[j] + i_ * g_;
        ca[j] = cc;
        hv[j] = o_ * fminf(fmaxf(cc, -1.f), 1.f);
        pk.s[j] = f2bf(hv[j]);
      }
      size_t qi = (((size_t)((p ^ 1) * 2 + dir) * 32 + b4) * 1024 + col0) >> 2;
      __hip_atomic_store((unsigned long long*)hbuf + qi, pk.u,
                         __ATOMIC_RELAXED, __HIP_MEMORY_SCOPE_AGENT);
      asm volatile("s_waitcnt vmcnt(0)" ::: "memory");   // h stores acked (y NOT in flight)
      if (tid == 0)
        __hip_atomic_store(seq + wid * 32, ts + 2, __ATOMIC_RELAXED, __HIP_MEMORY_SCOPE_AGENT);
      // y-store after publish: its ack is off the critical path
      size_t yi = ((size_t)(t * 32 + b4)) * 2048 + dir * 1024 + col0;
      if (LAST) {
        float4 f4; f4.x = hv[0]; f4.y = hv[1]; f4.z = hv[2]; f4.w = hv[3];
        *(float4*)((float*)yout + yi) = f4;
      } else {
        short4v ys; ys.x = pk.s[0]; ys.y = pk.s[1]; ys.z = pk.s[2]; ys.w = pk.s[3];
        *(short4v*)((short*)yout + yi) = ys;
      }
      if (ts < 511) {
        // prefetch next step's gx (completes during next seqwait)
        const int tn = dir ? (511 - (ts + 1)) : (ts + 1);
        const short* gp = gx + ((size_t)(tn * 32 + b4)) * 8192 + dir * 4096 + col0;
        pgi = *(const short4v*)(gp);
        pgf = *(const short4v*)(gp + 1024);
        pgg = *(const short4v*)(gp + 2048);
        pgo = *(const short4v*)(gp + 3072);
      }
    }
    p ^= 1;
  }
}

// ---------------- host ----------------
extern "C" void kernel_launch(void* const* d_in, const int* in_sizes, int n_in,
                              void* d_out, int out_size, void* d_ws, size_t ws_size,
                              hipStream_t stream)
{
  const float* x  = (const float*)d_in[0];
  const float* h0 = (const float*)d_in[1];
  const float* c0 = (const float*)d_in[2];
  auto W = [&](int l, int d, int k) { return (const float*)d_in[3 + l * 8 + d * 4 + k]; };
  // k: 0=w_ih, 1=w_hh, 2=b_ih, 3=b_hh

  char* base = (char*)d_ws;
  size_t off = 0;
  auto alloc = [&](size_t bytes) {
    void* p = base + off;
    off = (off + bytes + 255) & ~(size_t)255;
    return p;
  };
  short* xb    = (short*)alloc(16384ull * 320 * 2);
  short* wih0  = (short*)alloc(8192ull * 320 * 2);
  short* wih1  = (short*)alloc(8192ull * 2048 * 2);
  short* wih2  = (short*)alloc(8192ull * 2048 * 2);
  short* whh0  = (short*)alloc(8192ull * 1024 * 2);
  short* whh1  = (short*)alloc(8192ull * 1024 * 2);
  short* whh2  = (short*)alloc(8192ull * 1024 * 2);
  float* bias0 = (float*)alloc(8192ull * 4);
  float* bias1 = (float*)alloc(8192ull * 4);
  float* bias2 = (float*)alloc(8192ull * 4);
  short* gx    = (short*)alloc(16384ull * 8192 * 2);
  short* y1    = (short*)alloc(16384ull * 2048 * 2);
  short* y2    = (short*)alloc(16384ull * 2048 * 2);
  short* hbuf  = (short*)alloc(2ull * 2 * 32 * 1024 * 2);
  int*   bar   = (int*)alloc(2ull * 128 * 32 * 4);
  (void)ws_size; (void)in_sizes; (void)n_in; (void)out_size;

  auto cvt = [&](const float* s, short* d, size_t n) {
    size_t want = (n / 4 + 255) / 256;
    int blocks = (int)(want > 2048 ? 2048 : want);
    k_cvt<<<dim3(blocks), dim3(256), 0, stream>>>(s, d, (int)n);
  };

  cvt(x, xb, 16384ull * 320);
  short* wihs[3] = { wih0, wih1, wih2 };
  short* whhs[3] = { whh0, whh1, whh2 };
  float* biases[3] = { bias0, bias1, bias2 };
  for (int l = 0; l < 3; ++l) {
    size_t kin = (l == 0) ? 320 : 2048;
    cvt(W(l, 0, 0), wihs[l],                  4096 * kin);
    cvt(W(l, 1, 0), wihs[l] + 4096 * kin,     4096 * kin);
    cvt(W(l, 0, 1), whhs[l],                  4096ull * 1024);
    cvt(W(l, 1, 1), whhs[l] + 4096ull * 1024, 4096ull * 1024);
    k_bias<<<dim3(32), dim3(256), 0, stream>>>(W(l, 0, 2), W(l, 0, 3), W(l, 1, 2), W(l, 1, 3), biases[l]);
  }

  const int M = 16384, N = 8192;

  // ---- layer 0 ----
  k_gemm<<<dim3((M / 128) * (N / 128)), dim3(256), 0, stream>>>(xb, wih0, bias0, gx, M, N, 320);
  k_zero<<<dim3(32), dim3(256), 0, stream>>>(bar);
  {
    const short* gxc = gx; const short* whhc = whh0; short* hb = hbuf;
    void* yo = (void*)y1; int layer = 0;
    void* args[] = { &gxc, &whhc, &h0, &c0, &hb, &yo, &layer, &bar };
    hipLaunchCooperativeKernel(k_scan<false>, dim3(256), dim3(256), args, 0, stream);
  }
  // ---- layer 1 ----
  k_gemm<<<dim3((M / 128) * (N / 128)), dim3(256), 0, stream>>>(y1, wih1, bias1, gx, M, N, 2048);
  k_zero<<<dim3(32), dim3(256), 0, stream>>>(bar);
  {
    const short* gxc = gx; const short* whhc = whh1; short* hb = hbuf;
    void* yo = (void*)y2; int layer = 1;
    void* args[] = { &gxc, &whhc, &h0, &c0, &hb, &yo, &layer, &bar };
    hipLaunchCooperativeKernel(k_scan<false>, dim3(256), dim3(256), args, 0, stream);
  }
  // ---- layer 2 ----
  k_gemm<<<dim3((M / 128) * (N / 128)), dim3(256), 0, stream>>>(y2, wih2, bias2, gx, M, N, 2048);
  k_zero<<<dim3(32), dim3(256), 0, stream>>>(bar);
  {
    const short* gxc = gx; const short* whhc = whh2; short* hb = hbuf;
    void* yo = d_out; int layer = 2;
    void* args[] = { &gxc, &whhc, &h0, &c0, &hb, &yo, &layer, &bar };
    hipLaunchCooperativeKernel(k_scan<true>, dim3(256), dim3(256), args, 0, stream);
  }
}

// Round 7
// 12086.752 us; speedup vs baseline: 8.6282x; 1.0343x over previous
//
#include <hip/hip_runtime.h>

typedef __attribute__((ext_vector_type(8))) short short8;
typedef __attribute__((ext_vector_type(4))) short short4v;
typedef __attribute__((ext_vector_type(4))) float f32x4;

__device__ __forceinline__ short f2bf(float x) {
  union { float f; unsigned u; } v; v.f = x;
  unsigned r = v.u + 0x7fffu + ((v.u >> 16) & 1u);   // RNE
  return (short)(r >> 16);
}
__device__ __forceinline__ float bf2f(short b) {
  union { unsigned u; float f; } v; v.u = ((unsigned)(unsigned short)b) << 16;
  return v.f;
}

#define GLOAD_LDS16(g, l) __builtin_amdgcn_global_load_lds( \
    (const __attribute__((address_space(1))) void*)(g),     \
    (__attribute__((address_space(3))) void*)(l), 16, 0, 0)

// ---------------- f32 -> bf16 conversion ----------------
__global__ void k_cvt(const float* __restrict__ s, short* __restrict__ d, int n) {
  int stride = gridDim.x * blockDim.x * 4;
  for (int i = (blockIdx.x * blockDim.x + threadIdx.x) * 4; i < n; i += stride) {
    float4 v = *(const float4*)(s + i);
    short4v o;
    o.x = f2bf(v.x); o.y = f2bf(v.y); o.z = f2bf(v.z); o.w = f2bf(v.w);
    *(short4v*)(d + i) = o;
  }
}

// ---------------- combined bias (fwd 0:4096, rev 4096:8192) ----------------
__global__ void k_bias(const float* __restrict__ bif, const float* __restrict__ bhf,
                       const float* __restrict__ bir, const float* __restrict__ bhr,
                       float* __restrict__ o) {
  int i = blockIdx.x * 256 + threadIdx.x;
  o[i] = (i < 4096) ? (bif[i] + bhf[i]) : (bir[i - 4096] + bhr[i - 4096]);
}

// ---------------- zero the seq block (32KB) ----------------
__global__ void k_zero(int* __restrict__ p) { p[blockIdx.x * 256 + threadIdx.x] = 0; }

// ---------------- input GEMM: C[M][N] = A[M][K] * Bt[N][K]^T + bias, bf16 out ----
__global__ void __launch_bounds__(256) k_gemm(
    const short* __restrict__ A, const short* __restrict__ Bt,
    const float* __restrict__ bias, short* __restrict__ C,
    int M, int N, int K)
{
  __shared__ short Al[128 * 64];
  __shared__ short Bl[128 * 64];
  const int nm = M >> 7;
  int wg = blockIdx.x;
  int q = gridDim.x >> 3;                   // gridDim.x % 8 == 0 (8192)
  wg = (wg & 7) * q + (wg >> 3);            // XCD-aware swizzle (bijective)
  const int mt = wg % nm, nt = wg / nm;
  const int tid = threadIdx.x, lane = tid & 63, w = tid >> 6;
  const int wr = w >> 1, wc = w & 1;
  const short* Ab = A + (size_t)(mt * 128) * K;
  const short* Bb = Bt + (size_t)(nt * 128) * K;
  f32x4 acc[4][4] = {};
  const int lrow = lane >> 3, lseg = lane & 7;

  for (int kt = 0; kt < K; kt += 64) {
#pragma unroll
    for (int s = 0; s < 4; ++s) {
      int chunk = s * 4 + w;                // wave-uniform LDS base
      int r = chunk * 8 + lrow;
      GLOAD_LDS16(Ab + (size_t)r * K + kt + lseg * 8, &Al[chunk * 512]);
      GLOAD_LDS16(Bb + (size_t)r * K + kt + lseg * 8, &Bl[chunk * 512]);
    }
    __syncthreads();
#pragma unroll
    for (int kk = 0; kk < 2; ++kk) {
      short8 af[4], bfr[4];
#pragma unroll
      for (int i = 0; i < 4; ++i) {
        af[i]  = *(const short8*)&Al[(wr * 64 + i * 16 + (lane & 15)) * 64 + kk * 32 + (lane >> 4) * 8];
        bfr[i] = *(const short8*)&Bl[(wc * 64 + i * 16 + (lane & 15)) * 64 + kk * 32 + (lane >> 4) * 8];
      }
#pragma unroll
      for (int i = 0; i < 4; ++i)
#pragma unroll
        for (int j = 0; j < 4; ++j)
          acc[i][j] = __builtin_amdgcn_mfma_f32_16x16x32_bf16(af[i], bfr[j], acc[i][j], 0, 0, 0);
    }
    __syncthreads();
  }

  const int r0 = mt * 128 + wr * 64, c0n = nt * 128 + wc * 64;
#pragma unroll
  for (int i = 0; i < 4; ++i) {
#pragma unroll
    for (int j = 0; j < 4; ++j) {
      int col = c0n + j * 16 + (lane & 15);
      float bv = bias[col];
#pragma unroll
      for (int r = 0; r < 4; ++r) {
        int row = r0 + i * 16 + (lane >> 4) * 4 + r;
        C[(size_t)row * N + col] = f2bf(acc[i][j][r] + bv);
      }
    }
  }
}

// ---------------- split poll: wave kq validates seq words [kq*32, kq*32+32) ---
// Caller must __syncthreads() after: the barrier joins the 4 slices into the
// all-128 guarantee (r5 had every wave polling all 128 -> 4x the MALL traffic
// on the same 128 hot lines during every discovery window).
__device__ __forceinline__ void seqwait_slice(int* seqbase, int target, int kq, int lane) {
  if (lane < 32) {
    int* sp = seqbase + (kq * 32 + lane) * 32;
    while (__hip_atomic_load(sp, __ATOMIC_RELAXED, __HIP_MEMORY_SCOPE_AGENT) < target)
      __builtin_amdgcn_s_sleep(1);
  }
  asm volatile("" ::: "memory");
}

// ---------------- persistent bidirectional scan ----------------
// 256 WGs x 256 threads. WG = (dir = blk>>7, wid = blk&127) owns h-cols [wid*8, wid*8+8)
// == 32 gate rows (8 per gate type). K-SPLIT across waves: wave kq handles
// k in [kq*256, kq*256+256) for ALL four 16x16 quadrants; A-frags (16 x short8
// = 64 VGPR) fully register-resident so all 32 b64 coherence-point loads issue
// in ONE batch. Partials reduced via LDS (stride 35: <=2-way on b128 writes).
// Protocol (r5-proven): producer h atomic-stores -> vmcnt(0) ack -> seq store;
// consumer: slice-poll + barrier (all 128 seq >= ts+1), then b64 agent loads.
template <bool LAST>
__global__ void __launch_bounds__(256, 1) k_scan(
    const short* __restrict__ gx,     // [16384][8192] bf16 (bias included)
    const short* __restrict__ whh,    // [8192][1024] bf16 (fwd rows 0:4096, rev 4096:8192)
    const float* __restrict__ h0,     // [6][32][1024]
    const float* __restrict__ c0,
    short* __restrict__ hbuf,         // [2 parity][2 dir][32][1024] bf16
    void* __restrict__ yout,          // bf16 [512][32][2048] or f32 (LAST)
    int layer, int* __restrict__ bar) // seq: [2 dir][128] ints @ 32-int stride
{
  const int tid = threadIdx.x, lane = tid & 63, kq = tid >> 6;   // wave = k-quarter
  const int dir = blockIdx.x >> 7, wid = blockIdx.x & 127;
  const int hc0 = wid * 8;
  __shared__ float part[4][32][35];         // [kq][gate][batch]
  int* seq = bar + dir * 128 * 32;

  // --- weights: wave kq, n-tile ni: col = ni*16+(lane&15), k = kq*256+ks*32+(lane>>4)*8 ---
  short8 wfr[16];
#pragma unroll
  for (int ni = 0; ni < 2; ++ni) {
    const int lcol = ni * 16 + (lane & 15);
    const int grow = dir * 4096 + (lcol >> 3) * 1024 + hc0 + (lcol & 7);
    const short* wp = whh + (size_t)grow * 1024 + kq * 256 + (lane >> 4) * 8;
#pragma unroll
    for (int ks = 0; ks < 8; ++ks) wfr[ni * 8 + ks] = *(const short8*)(wp + ks * 32);
  }
#pragma unroll
  for (int i = 0; i < 16; ++i) asm volatile("" : "+v"(wfr[i]));

  // --- state init: 64 active threads, each owns (batch b4, 4 h-cols) ---
  const int b4 = tid >> 1, cg = tid & 1, col0 = hc0 + cg * 4;
  float ca[4] = {0.f, 0.f, 0.f, 0.f};
  short4v pgi, pgf, pgg, pgo;               // prefetched gx for the upcoming step
  if (tid < 64) {
    const int sidx = ((2 * layer + dir) * 32 + b4) * 1024 + col0;
    float4 cv = *(const float4*)(c0 + sidx);
    ca[0] = cv.x; ca[1] = cv.y; ca[2] = cv.z; ca[3] = cv.w;
    float4 hv = *(const float4*)(h0 + sidx);
    union { unsigned long long u; short s[4]; } pk;
    pk.s[0] = f2bf(hv.x); pk.s[1] = f2bf(hv.y); pk.s[2] = f2bf(hv.z); pk.s[3] = f2bf(hv.w);
    size_t qi = (((size_t)dir * 32 + b4) * 1024 + col0) >> 2;    // parity 0
    __hip_atomic_store((unsigned long long*)hbuf + qi, pk.u,
                       __ATOMIC_RELAXED, __HIP_MEMORY_SCOPE_AGENT);
    asm volatile("s_waitcnt vmcnt(0)" ::: "memory");             // wave0 stores acked
  }
  if (tid == 0)
    __hip_atomic_store(seq + wid * 32, 1, __ATOMIC_RELAXED, __HIP_MEMORY_SCOPE_AGENT);
  if (tid < 64) {
    const int t0 = dir ? 511 : 0;
    const short* gp = gx + ((size_t)(t0 * 32 + b4)) * 8192 + dir * 4096 + col0;
    pgi = *(const short4v*)(gp);
    pgf = *(const short4v*)(gp + 1024);
    pgg = *(const short4v*)(gp + 2048);
    pgo = *(const short4v*)(gp + 3072);
  }
  const int arow = lane & 15;               // batch row within m-tile
  const int kw = (lane >> 4) * 2;           // ull offset of lane's k-slice

  int p = 0;
  for (int ts = 0; ts < 512; ++ts) {
    const int t = dir ? (511 - ts) : ts;

    seqwait_slice(seq, ts + 1, kq, lane);
    __syncthreads();                        // join 4 slices: all 128 confirmed

    // --- h A-frags: 32 independent b64 coherence-point loads, one batch ---
    unsigned long long* hb = (unsigned long long*)hbuf + (size_t)(p * 2 + dir) * 8192;
    short8 af[16];
#pragma unroll
    for (int mi = 0; mi < 2; ++mi) {
      const size_t rb = (size_t)(mi * 16 + arow) * 256 + kq * 64 + kw;
#pragma unroll
      for (int ks = 0; ks < 8; ++ks) {
        union { unsigned long long u[2]; short8 v; } tu;
        tu.u[0] = __hip_atomic_load(hb + rb + ks * 8,     __ATOMIC_RELAXED, __HIP_MEMORY_SCOPE_AGENT);
        tu.u[1] = __hip_atomic_load(hb + rb + ks * 8 + 1, __ATOMIC_RELAXED, __HIP_MEMORY_SCOPE_AGENT);
        af[mi * 8 + ks] = tu.v;
      }
    }
#pragma unroll
    for (int i = 0; i < 16; ++i) asm volatile("" : "+v"(af[i]));

    // --- partial gates for this k-quarter: all 4 quadrants ---
    f32x4 acc[2][2] = {};
#pragma unroll
    for (int ks = 0; ks < 8; ++ks) {
      acc[0][0] = __builtin_amdgcn_mfma_f32_16x16x32_bf16(af[ks],     wfr[ks],     acc[0][0], 0, 0, 0);
      acc[1][0] = __builtin_amdgcn_mfma_f32_16x16x32_bf16(af[8 + ks], wfr[ks],     acc[1][0], 0, 0, 0);
      acc[0][1] = __builtin_amdgcn_mfma_f32_16x16x32_bf16(af[ks],     wfr[8 + ks], acc[0][1], 0, 0, 0);
      acc[1][1] = __builtin_amdgcn_mfma_f32_16x16x32_bf16(af[8 + ks], wfr[8 + ks], acc[1][1], 0, 0, 0);
    }
#pragma unroll
    for (int mi = 0; mi < 2; ++mi)
#pragma unroll
      for (int ni = 0; ni < 2; ++ni)
#pragma unroll
        for (int r = 0; r < 4; ++r)
          part[kq][ni * 16 + (lane & 15)][mi * 16 + (lane >> 4) * 4 + r] = acc[mi][ni][r];
    __syncthreads();

    // --- elementwise update: thread (tid<64) owns (b=b4, cols col0..col0+3) ---
    if (tid < 64) {
      const int c7 = cg * 4;
      float hv[4];
      union { unsigned long long u; short s[4]; } pk;
#pragma unroll
      for (int j = 0; j < 4; ++j) {
        float gi = part[0][c7 + j][b4]      + part[1][c7 + j][b4]      + part[2][c7 + j][b4]      + part[3][c7 + j][b4]      + bf2f(pgi[j]);
        float gf = part[0][8 + c7 + j][b4]  + part[1][8 + c7 + j][b4]  + part[2][8 + c7 + j][b4]  + part[3][8 + c7 + j][b4]  + bf2f(pgf[j]);
        float gg = part[0][16 + c7 + j][b4] + part[1][16 + c7 + j][b4] + part[2][16 + c7 + j][b4] + part[3][16 + c7 + j][b4] + bf2f(pgg[j]);
        float go = part[0][24 + c7 + j][b4] + part[1][24 + c7 + j][b4] + part[2][24 + c7 + j][b4] + part[3][24 + c7 + j][b4] + bf2f(pgo[j]);
        float i_ = fminf(fmaxf(0.2f * gi + 0.5f, 0.f), 1.f);
        float f_ = fminf(fmaxf(0.2f * gf + 0.5f, 0.f), 1.f);
        float g_ = fminf(fmaxf(gg, -1.f), 1.f);
        float o_ = fminf(fmaxf(0.2f * go + 0.5f, 0.f), 1.f);
        float cc = f_ * ca[j] + i_ * g_;
        ca[j] = cc;
        hv[j] = o_ * fminf(fmaxf(cc, -1.f), 1.f);
        pk.s[j] = f2bf(hv[j]);
      }
      size_t qi = (((size_t)((p ^ 1) * 2 + dir) * 32 + b4) * 1024 + col0) >> 2;
      __hip_atomic_store((unsigned long long*)hbuf + qi, pk.u,
                         __ATOMIC_RELAXED, __HIP_MEMORY_SCOPE_AGENT);
      asm volatile("s_waitcnt vmcnt(0)" ::: "memory");   // h stores acked (y NOT in flight)
      if (tid == 0)
        __hip_atomic_store(seq + wid * 32, ts + 2, __ATOMIC_RELAXED, __HIP_MEMORY_SCOPE_AGENT);
      // y-store after publish: its ack is off the critical path
      size_t yi = ((size_t)(t * 32 + b4)) * 2048 + dir * 1024 + col0;
      if (LAST) {
        float4 f4; f4.x = hv[0]; f4.y = hv[1]; f4.z = hv[2]; f4.w = hv[3];
        *(float4*)((float*)yout + yi) = f4;
      } else {
        short4v ys; ys.x = pk.s[0]; ys.y = pk.s[1]; ys.z = pk.s[2]; ys.w = pk.s[3];
        *(short4v*)((short*)yout + yi) = ys;
      }
      if (ts < 511) {
        // prefetch next step's gx (completes during next poll window)
        const int tn = dir ? (511 - (ts + 1)) : (ts + 1);
        const short* gp = gx + ((size_t)(tn * 32 + b4)) * 8192 + dir * 4096 + col0;
        pgi = *(const short4v*)(gp);
        pgf = *(const short4v*)(gp + 1024);
        pgg = *(const short4v*)(gp + 2048);
        pgo = *(const short4v*)(gp + 3072);
      }
    }
    p ^= 1;
  }
}

// ---------------- host ----------------
extern "C" void kernel_launch(void* const* d_in, const int* in_sizes, int n_in,
                              void* d_out, int out_size, void* d_ws, size_t ws_size,
                              hipStream_t stream)
{
  const float* x  = (const float*)d_in[0];
  const float* h0 = (const float*)d_in[1];
  const float* c0 = (const float*)d_in[2];
  auto W = [&](int l, int d, int k) { return (const float*)d_in[3 + l * 8 + d * 4 + k]; };
  // k: 0=w_ih, 1=w_hh, 2=b_ih, 3=b_hh

  char* base = (char*)d_ws;
  size_t off = 0;
  auto alloc = [&](size_t bytes) {
    void* p = base + off;
    off = (off + bytes + 255) & ~(size_t)255;
    return p;
  };
  short* xb    = (short*)alloc(16384ull * 320 * 2);
  short* wih0  = (short*)alloc(8192ull * 320 * 2);
  short* wih1  = (short*)alloc(8192ull * 2048 * 2);
  short* wih2  = (short*)alloc(8192ull * 2048 * 2);
  short* whh0  = (short*)alloc(8192ull * 1024 * 2);
  short* whh1  = (short*)alloc(8192ull * 1024 * 2);
  short* whh2  = (short*)alloc(8192ull * 1024 * 2);
  float* bias0 = (float*)alloc(8192ull * 4);
  float* bias1 = (float*)alloc(8192ull * 4);
  float* bias2 = (float*)alloc(8192ull * 4);
  short* gx    = (short*)alloc(16384ull * 8192 * 2);
  short* y1    = (short*)alloc(16384ull * 2048 * 2);
  short* y2    = (short*)alloc(16384ull * 2048 * 2);
  short* hbuf  = (short*)alloc(2ull * 2 * 32 * 1024 * 2);
  int*   bar   = (int*)alloc(2ull * 128 * 32 * 4);
  (void)ws_size; (void)in_sizes; (void)n_in; (void)out_size;

  auto cvt = [&](const float* s, short* d, size_t n) {
    size_t want = (n / 4 + 255) / 256;
    int blocks = (int)(want > 2048 ? 2048 : want);
    k_cvt<<<dim3(blocks), dim3(256), 0, stream>>>(s, d, (int)n);
  };

  cvt(x, xb, 16384ull * 320);
  short* wihs[3] = { wih0, wih1, wih2 };
  short* whhs[3] = { whh0, whh1, whh2 };
  float* biases[3] = { bias0, bias1, bias2 };
  for (int l = 0; l < 3; ++l) {
    size_t kin = (l == 0) ? 320 : 2048;
    cvt(W(l, 0, 0), wihs[l],                  4096 * kin);
    cvt(W(l, 1, 0), wihs[l] + 4096 * kin,     4096 * kin);
    cvt(W(l, 0, 1), whhs[l],                  4096ull * 1024);
    cvt(W(l, 1, 1), whhs[l] + 4096ull * 1024, 4096ull * 1024);
    k_bias<<<dim3(32), dim3(256), 0, stream>>>(W(l, 0, 2), W(l, 0, 3), W(l, 1, 2), W(l, 1, 3), biases[l]);
  }

  const int M = 16384, N = 8192;

  // ---- layer 0 ----
  k_gemm<<<dim3((M / 128) * (N / 128)), dim3(256), 0, stream>>>(xb, wih0, bias0, gx, M, N, 320);
  k_zero<<<dim3(32), dim3(256), 0, stream>>>(bar);
  {
    const short* gxc = gx; const short* whhc = whh0; short* hb = hbuf;
    void* yo = (void*)y1; int layer = 0;
    void* args[] = { &gxc, &whhc, &h0, &c0, &hb, &yo, &layer, &bar };
    hipLaunchCooperativeKernel(k_scan<false>, dim3(256), dim3(256), args, 0, stream);
  }
  // ---- layer 1 ----
  k_gemm<<<dim3((M / 128) * (N / 128)), dim3(256), 0, stream>>>(y1, wih1, bias1, gx, M, N, 2048);
  k_zero<<<dim3(32), dim3(256), 0, stream>>>(bar);
  {
    const short* gxc = gx; const short* whhc = whh1; short* hb = hbuf;
    void* yo = (void*)y2; int layer = 1;
    void* args[] = { &gxc, &whhc, &h0, &c0, &hb, &yo, &layer, &bar };
    hipLaunchCooperativeKernel(k_scan<false>, dim3(256), dim3(256), args, 0, stream);
  }
  // ---- layer 2 ----
  k_gemm<<<dim3((M / 128) * (N / 128)), dim3(256), 0, stream>>>(y2, wih2, bias2, gx, M, N, 2048);
  k_zero<<<dim3(32), dim3(256), 0, stream>>>(bar);
  {
    const short* gxc = gx; const short* whhc = whh2; short* hb = hbuf;
    void* yo = d_out; int layer = 2;
    void* args[] = { &gxc, &whhc, &h0, &c0, &hb, &yo, &layer, &bar };
    hipLaunchCooperativeKernel(k_scan<true>, dim3(256), dim3(256), args, 0, stream);
  }
}

// Round 8
// 11994.038 us; speedup vs baseline: 8.6949x; 1.0077x over previous
//
#include <hip/hip_runtime.h>

typedef __attribute__((ext_vector_type(8))) short short8;
typedef __attribute__((ext_vector_type(4))) short short4v;
typedef __attribute__((ext_vector_type(4))) float f32x4;
typedef unsigned long long u64;

__device__ __forceinline__ short f2bf(float x) {
  union { float f; unsigned u; } v; v.f = x;
  unsigned r = v.u + 0x7fffu + ((v.u >> 16) & 1u);   // RNE
  return (short)(r >> 16);
}
__device__ __forceinline__ float bf2f(short b) {
  union { unsigned u; float f; } v; v.u = ((unsigned)(unsigned short)b) << 16;
  return v.f;
}

#define GLOAD_LDS16(g, l) __builtin_amdgcn_global_load_lds( \
    (const __attribute__((address_space(1))) void*)(g),     \
    (__attribute__((address_space(3))) void*)(l), 16, 0, 0)

// ---------------- f32 -> bf16 conversion ----------------
__global__ void k_cvt(const float* __restrict__ s, short* __restrict__ d, int n) {
  int stride = gridDim.x * blockDim.x * 4;
  for (int i = (blockIdx.x * blockDim.x + threadIdx.x) * 4; i < n; i += stride) {
    float4 v = *(const float4*)(s + i);
    short4v o;
    o.x = f2bf(v.x); o.y = f2bf(v.y); o.z = f2bf(v.z); o.w = f2bf(v.w);
    *(short4v*)(d + i) = o;
  }
}

// ---------------- combined bias (fwd 0:4096, rev 4096:8192) ----------------
__global__ void k_bias(const float* __restrict__ bif, const float* __restrict__ bhf,
                       const float* __restrict__ bir, const float* __restrict__ bhr,
                       float* __restrict__ o) {
  int i = blockIdx.x * 256 + threadIdx.x;
  o[i] = (i < 4096) ? (bif[i] + bhf[i]) : (bir[i - 4096] + bhr[i - 4096]);
}

// ---------------- zero the seq block (16KB) ----------------
__global__ void k_zero(int* __restrict__ p) { p[blockIdx.x * 256 + threadIdx.x] = 0; }

// ---------------- input GEMM: C[M][N] = A[M][K] * Bt[N][K]^T + bias, bf16 out ----
__global__ void __launch_bounds__(256) k_gemm(
    const short* __restrict__ A, const short* __restrict__ Bt,
    const float* __restrict__ bias, short* __restrict__ C,
    int M, int N, int K)
{
  __shared__ short Al[128 * 64];
  __shared__ short Bl[128 * 64];
  const int nm = M >> 7;
  int wg = blockIdx.x;
  int q = gridDim.x >> 3;                   // gridDim.x % 8 == 0 (8192)
  wg = (wg & 7) * q + (wg >> 3);            // XCD-aware swizzle (bijective)
  const int mt = wg % nm, nt = wg / nm;
  const int tid = threadIdx.x, lane = tid & 63, w = tid >> 6;
  const int wr = w >> 1, wc = w & 1;
  const short* Ab = A + (size_t)(mt * 128) * K;
  const short* Bb = Bt + (size_t)(nt * 128) * K;
  f32x4 acc[4][4] = {};
  const int lrow = lane >> 3, lseg = lane & 7;

  for (int kt = 0; kt < K; kt += 64) {
#pragma unroll
    for (int s = 0; s < 4; ++s) {
      int chunk = s * 4 + w;                // wave-uniform LDS base
      int r = chunk * 8 + lrow;
      GLOAD_LDS16(Ab + (size_t)r * K + kt + lseg * 8, &Al[chunk * 512]);
      GLOAD_LDS16(Bb + (size_t)r * K + kt + lseg * 8, &Bl[chunk * 512]);
    }
    __syncthreads();
#pragma unroll
    for (int kk = 0; kk < 2; ++kk) {
      short8 af[4], bfr[4];
#pragma unroll
      for (int i = 0; i < 4; ++i) {
        af[i]  = *(const short8*)&Al[(wr * 64 + i * 16 + (lane & 15)) * 64 + kk * 32 + (lane >> 4) * 8];
        bfr[i] = *(const short8*)&Bl[(wc * 64 + i * 16 + (lane & 15)) * 64 + kk * 32 + (lane >> 4) * 8];
      }
#pragma unroll
      for (int i = 0; i < 4; ++i)
#pragma unroll
        for (int j = 0; j < 4; ++j)
          acc[i][j] = __builtin_amdgcn_mfma_f32_16x16x32_bf16(af[i], bfr[j], acc[i][j], 0, 0, 0);
    }
    __syncthreads();
  }

  const int r0 = mt * 128 + wr * 64, c0n = nt * 128 + wc * 64;
#pragma unroll
  for (int i = 0; i < 4; ++i) {
#pragma unroll
    for (int j = 0; j < 4; ++j) {
      int col = c0n + j * 16 + (lane & 15);
      float bv = bias[col];
#pragma unroll
      for (int r = 0; r < 4; ++r) {
        int row = r0 + i * 16 + (lane >> 4) * 4 + r;
        C[(size_t)row * N + col] = f2bf(acc[i][j][r] + bv);
      }
    }
  }
}

// ---------------- persistent bidirectional scan, FAT-WG (512 thr) ------------
// 128 WGs x 512 threads (plain launch; no grid.sync anywhere, 128 blocks <= 256
// CUs => trivially co-resident). WG = (dir = blk>>6, wid = blk&63) owns h-cols
// [wid*16, wid*16+16) == 64 gate rows. K split 8 ways across waves: wave kq
// covers k in [kq*128, kq*128+128) for all 2x4 16x16 quadrants; A-frags
// (8 x short8 = 32 VGPR) register-resident -> all 16 b64 coherence-point loads
// issue in ONE batch. Halves MALL h-broadcast traffic vs 256-WG layout
// (8 MB/step) and halves seq lines (64/dir).
// Protocol (r5/r7-proven): producer h atomic-stores -> vmcnt(0) ack (both
// update waves) -> barrier -> tid0 seq store; consumer: per-wave slice poll
// (8 lines each) + barrier, then b64 agent loads.
template <bool LAST>
__global__ void __launch_bounds__(512, 1) k_scan(
    const short* __restrict__ gx,     // [16384][8192] bf16 (bias included)
    const short* __restrict__ whh,    // [8192][1024] bf16 (fwd rows 0:4096, rev 4096:8192)
    const float* __restrict__ h0,     // [6][32][1024]
    const float* __restrict__ c0,
    short* __restrict__ hbuf,         // [2 parity][2 dir][32][1024] bf16
    void* __restrict__ yout,          // bf16 [512][32][2048] or f32 (LAST)
    int layer, int* __restrict__ bar) // seq: [2 dir][64] ints @ 32-int stride
{
  const int tid = threadIdx.x, lane = tid & 63, kq = tid >> 6;   // 8 waves = k-eighths
  const int dir = blockIdx.x >> 6, wid = blockIdx.x & 63;
  const int hc0 = wid * 16;
  extern __shared__ float part[];           // [8][64][35]
  int* seq = bar + dir * 64 * 32;

  // --- weights: wave kq, gate ni(0..3): local row = ni*16+(lane&15) ---
  short8 wfr[16];
#pragma unroll
  for (int ni = 0; ni < 4; ++ni) {
    const int l15 = lane & 15;
    const int grow = dir * 4096 + ni * 1024 + hc0 + l15;         // gate ni, col l15
    const short* wp = whh + (size_t)grow * 1024 + kq * 128 + (lane >> 4) * 8;
#pragma unroll
    for (int ks = 0; ks < 4; ++ks) wfr[ni * 4 + ks] = *(const short8*)(wp + ks * 32);
  }
#pragma unroll
  for (int i = 0; i < 16; ++i) asm volatile("" : "+v"(wfr[i]));

  // --- state init: 128 active threads, each owns (batch b4, 4 h-cols) ---
  const int b4 = tid >> 2, cg = tid & 3, col0 = hc0 + cg * 4;
  float ca[4] = {0.f, 0.f, 0.f, 0.f};
  short4v pgi, pgf, pgg, pgo;               // prefetched gx for the upcoming step
  if (tid < 128) {
    const int sidx = ((2 * layer + dir) * 32 + b4) * 1024 + col0;
    float4 cv = *(const float4*)(c0 + sidx);
    ca[0] = cv.x; ca[1] = cv.y; ca[2] = cv.z; ca[3] = cv.w;
    float4 hv = *(const float4*)(h0 + sidx);
    union { u64 u; short s[4]; } pk;
    pk.s[0] = f2bf(hv.x); pk.s[1] = f2bf(hv.y); pk.s[2] = f2bf(hv.z); pk.s[3] = f2bf(hv.w);
    size_t qi = (size_t)dir * 8192 + (size_t)b4 * 256 + wid * 4 + cg;  // parity 0
    __hip_atomic_store((u64*)hbuf + qi, pk.u,
                       __ATOMIC_RELAXED, __HIP_MEMORY_SCOPE_AGENT);
    asm volatile("s_waitcnt vmcnt(0)" ::: "memory");             // stores acked
  }
  __syncthreads();
  if (tid == 0)
    __hip_atomic_store(seq + wid * 32, 1, __ATOMIC_RELAXED, __HIP_MEMORY_SCOPE_AGENT);
  if (tid < 128) {
    const int t0 = dir ? 511 : 0;
    const short* gp = gx + ((size_t)(t0 * 32 + b4)) * 8192 + dir * 4096 + col0;
    pgi = *(const short4v*)(gp);
    pgf = *(const short4v*)(gp + 1024);
    pgg = *(const short4v*)(gp + 2048);
    pgo = *(const short4v*)(gp + 3072);
  }

  int p = 0;
  for (int ts = 0; ts < 512; ++ts) {
    const int t = dir ? (511 - ts) : ts;

    // --- slice poll: wave kq validates seq lines [kq*8, kq*8+8) ---
    if (lane < 8) {
      int* sp = seq + (kq * 8 + lane) * 32;
      while (__hip_atomic_load(sp, __ATOMIC_RELAXED, __HIP_MEMORY_SCOPE_AGENT) < ts + 1)
        __builtin_amdgcn_s_sleep(1);
    }
    asm volatile("" ::: "memory");
    __syncthreads();                        // join 8 slices: all 64 confirmed

    // --- h A-frags: 16 independent b64 coherence-point loads, one batch ---
    u64* hb = (u64*)hbuf + (size_t)(p * 2 + dir) * 8192;
    short8 af[8];
#pragma unroll
    for (int mi = 0; mi < 2; ++mi) {
      const size_t rb = (size_t)(mi * 16 + (lane & 15)) * 256 + kq * 32 + (lane >> 4) * 2;
#pragma unroll
      for (int ks = 0; ks < 4; ++ks) {
        union { u64 u[2]; short8 v; } tu;
        tu.u[0] = __hip_atomic_load(hb + rb + ks * 8,     __ATOMIC_RELAXED, __HIP_MEMORY_SCOPE_AGENT);
        tu.u[1] = __hip_atomic_load(hb + rb + ks * 8 + 1, __ATOMIC_RELAXED, __HIP_MEMORY_SCOPE_AGENT);
        af[mi * 4 + ks] = tu.v;
      }
    }
#pragma unroll
    for (int i = 0; i < 8; ++i) asm volatile("" : "+v"(af[i]));

    // --- partial gates for this k-eighth: 2 m-tiles x 4 gates ---
    f32x4 acc[2][4] = {};
#pragma unroll
    for (int ks = 0; ks < 4; ++ks) {
#pragma unroll
      for (int mi = 0; mi < 2; ++mi)
#pragma unroll
        for (int ni = 0; ni < 4; ++ni)
          acc[mi][ni] = __builtin_amdgcn_mfma_f32_16x16x32_bf16(
              af[mi * 4 + ks], wfr[ni * 4 + ks], acc[mi][ni], 0, 0, 0);
    }
#pragma unroll
    for (int mi = 0; mi < 2; ++mi)
#pragma unroll
      for (int ni = 0; ni < 4; ++ni)
#pragma unroll
        for (int r = 0; r < 4; ++r)
          part[(kq * 64 + ni * 16 + (lane & 15)) * 35 + mi * 16 + (lane >> 4) * 4 + r] = acc[mi][ni][r];
    __syncthreads();

    // --- elementwise update: thread (tid<128) owns (b=b4, cols col0..col0+3) ---
    union { u64 u; short s[4]; } pk;
    float hv[4];
    if (tid < 128) {
      const int c7 = cg * 4;
#pragma unroll
      for (int j = 0; j < 4; ++j) {
        float gi = bf2f(pgi[j]), gf = bf2f(pgf[j]), gg = bf2f(pgg[j]), go = bf2f(pgo[j]);
#pragma unroll
        for (int q = 0; q < 8; ++q) {
          gi += part[(q * 64      + c7 + j) * 35 + b4];
          gf += part[(q * 64 + 16 + c7 + j) * 35 + b4];
          gg += part[(q * 64 + 32 + c7 + j) * 35 + b4];
          go += part[(q * 64 + 48 + c7 + j) * 35 + b4];
        }
        float i_ = fminf(fmaxf(0.2f * gi + 0.5f, 0.f), 1.f);
        float f_ = fminf(fmaxf(0.2f * gf + 0.5f, 0.f), 1.f);
        float g_ = fminf(fmaxf(gg, -1.f), 1.f);
        float o_ = fminf(fmaxf(0.2f * go + 0.5f, 0.f), 1.f);
        float cc = f_ * ca[j] + i_ * g_;
        ca[j] = cc;
        hv[j] = o_ * fminf(fmaxf(cc, -1.f), 1.f);
        pk.s[j] = f2bf(hv[j]);
      }
      size_t qi = (size_t)((p ^ 1) * 2 + dir) * 8192 + (size_t)b4 * 256 + wid * 4 + cg;
      __hip_atomic_store((u64*)hbuf + qi, pk.u,
                         __ATOMIC_RELAXED, __HIP_MEMORY_SCOPE_AGENT);
      asm volatile("s_waitcnt vmcnt(0)" ::: "memory");   // h stores acked
    }
    __syncthreads();                        // both update waves acked
    if (tid == 0)
      __hip_atomic_store(seq + wid * 32, ts + 2, __ATOMIC_RELAXED, __HIP_MEMORY_SCOPE_AGENT);
    if (tid < 128) {
      // y-store + next gx prefetch: off the critical path
      size_t yi = ((size_t)(t * 32 + b4)) * 2048 + dir * 1024 + col0;
      if (LAST) {
        float4 f4; f4.x = hv[0]; f4.y = hv[1]; f4.z = hv[2]; f4.w = hv[3];
        *(float4*)((float*)yout + yi) = f4;
      } else {
        short4v ys; ys.x = pk.s[0]; ys.y = pk.s[1]; ys.z = pk.s[2]; ys.w = pk.s[3];
        *(short4v*)((short*)yout + yi) = ys;
      }
      if (ts < 511) {
        const int tn = dir ? (511 - (ts + 1)) : (ts + 1);
        const short* gp = gx + ((size_t)(tn * 32 + b4)) * 8192 + dir * 4096 + col0;
        pgi = *(const short4v*)(gp);
        pgf = *(const short4v*)(gp + 1024);
        pgg = *(const short4v*)(gp + 2048);
        pgo = *(const short4v*)(gp + 3072);
      }
    }
    p ^= 1;
  }
}

// ---------------- host ----------------
extern "C" void kernel_launch(void* const* d_in, const int* in_sizes, int n_in,
                              void* d_out, int out_size, void* d_ws, size_t ws_size,
                              hipStream_t stream)
{
  const float* x  = (const float*)d_in[0];
  const float* h0 = (const float*)d_in[1];
  const float* c0 = (const float*)d_in[2];
  auto W = [&](int l, int d, int k) { return (const float*)d_in[3 + l * 8 + d * 4 + k]; };
  // k: 0=w_ih, 1=w_hh, 2=b_ih, 3=b_hh

  char* base = (char*)d_ws;
  size_t off = 0;
  auto alloc = [&](size_t bytes) {
    void* p = base + off;
    off = (off + bytes + 255) & ~(size_t)255;
    return p;
  };
  short* xb    = (short*)alloc(16384ull * 320 * 2);
  short* wih0  = (short*)alloc(8192ull * 320 * 2);
  short* wih1  = (short*)alloc(8192ull * 2048 * 2);
  short* wih2  = (short*)alloc(8192ull * 2048 * 2);
  short* whh0  = (short*)alloc(8192ull * 1024 * 2);
  short* whh1  = (short*)alloc(8192ull * 1024 * 2);
  short* whh2  = (short*)alloc(8192ull * 1024 * 2);
  float* bias0 = (float*)alloc(8192ull * 4);
  float* bias1 = (float*)alloc(8192ull * 4);
  float* bias2 = (float*)alloc(8192ull * 4);
  short* gx    = (short*)alloc(16384ull * 8192 * 2);
  short* y1    = (short*)alloc(16384ull * 2048 * 2);
  short* y2    = (short*)alloc(16384ull * 2048 * 2);
  short* hbuf  = (short*)alloc(2ull * 2 * 32 * 1024 * 2);
  int*   bar   = (int*)alloc(2ull * 64 * 32 * 4);
  (void)ws_size; (void)in_sizes; (void)n_in; (void)out_size;

  auto cvt = [&](const float* s, short* d, size_t n) {
    size_t want = (n / 4 + 255) / 256;
    int blocks = (int)(want > 2048 ? 2048 : want);
    k_cvt<<<dim3(blocks), dim3(256), 0, stream>>>(s, d, (int)n);
  };

  cvt(x, xb, 16384ull * 320);
  short* wihs[3] = { wih0, wih1, wih2 };
  short* whhs[3] = { whh0, whh1, whh2 };
  float* biases[3] = { bias0, bias1, bias2 };
  for (int l = 0; l < 3; ++l) {
    size_t kin = (l == 0) ? 320 : 2048;
    cvt(W(l, 0, 0), wihs[l],                  4096 * kin);
    cvt(W(l, 1, 0), wihs[l] + 4096 * kin,     4096 * kin);
    cvt(W(l, 0, 1), whhs[l],                  4096ull * 1024);
    cvt(W(l, 1, 1), whhs[l] + 4096ull * 1024, 4096ull * 1024);
    k_bias<<<dim3(32), dim3(256), 0, stream>>>(W(l, 0, 2), W(l, 0, 3), W(l, 1, 2), W(l, 1, 3), biases[l]);
  }

  const int M = 16384, N = 8192;
  const int LDSB = 8 * 64 * 35 * 4;         // 71680 B dynamic LDS

  // ---- layer 0 ----
  k_gemm<<<dim3((M / 128) * (N / 128)), dim3(256), 0, stream>>>(xb, wih0, bias0, gx, M, N, 320);
  k_zero<<<dim3(16), dim3(256), 0, stream>>>(bar);
  k_scan<false><<<dim3(128), dim3(512), LDSB, stream>>>(gx, whh0, h0, c0, hbuf, (void*)y1, 0, bar);
  // ---- layer 1 ----
  k_gemm<<<dim3((M / 128) * (N / 128)), dim3(256), 0, stream>>>(y1, wih1, bias1, gx, M, N, 2048);
  k_zero<<<dim3(16), dim3(256), 0, stream>>>(bar);
  k_scan<false><<<dim3(128), dim3(512), LDSB, stream>>>(gx, whh1, h0, c0, hbuf, (void*)y2, 1, bar);
  // ---- layer 2 ----
  k_gemm<<<dim3((M / 128) * (N / 128)), dim3(256), 0, stream>>>(y2, wih2, bias2, gx, M, N, 2048);
  k_zero<<<dim3(16), dim3(256), 0, stream>>>(bar);
  k_scan<true><<<dim3(128), dim3(512), LDSB, stream>>>(gx, whh2, h0, c0, hbuf, d_out, 2, bar);
}